// Round 13
// baseline (150.121 us; speedup 1.0000x reference)
//
#include <hip/hip_runtime.h>
#include <cstdint>

// CQAttention: B=32, D=128, Lc=2048, Lq=256, f32 in/out.
// Pipeline (R13):
//   memset  : zero cq/qq accumulators (260KB)
//   k_tr x2 : bf16 copies + FUSED dot products (R13): Ct_bf [b][i][d],
//             Cbf [b][d][i], cq += partial C.w4C (atomicAdd per d0-block);
//             Qtw [b][j][d] (w4mlu folded), Qbf [b][d][j], qq += Q.w4Q.
//             Kills both k_cq launches + a full 64MB C re-read.
//   k_MT    : QT=16 (R13: 512 blocks -> 2 blocks/CU, was 256 -> 25% occ
//             cap, grid-starved like R8's k_AB). Single pass (exp(v-20)
//             const shift): S^T via MFMA + exp -> LDS P^T -> MT = C@P2 /
//             colsum -> bf16.
//   k_PAB   : fused row-softmax + A/Bt GEMMs with double-buffered LDS
//             B-panel staging (R12, proven: 190->149us). Untouched.
// Bt = S1 @ (S2^T @ Ct) associativity rewrite avoids the Lc x Lc matrix.

#define NB 32
#define ND 128
#define NLC 2048
#define NLQ 256
#define FNEG (-1.0e30f)
#define ESHIFT 20.0f

typedef __attribute__((ext_vector_type(8))) short bf16x8;
typedef __attribute__((ext_vector_type(4))) float f32x4;
#define MFMA16(a, b, c) __builtin_amdgcn_mfma_f32_16x16x32_bf16(a, b, c, 0, 0, 0)

__device__ __forceinline__ short f2bf(float x) {
  union { float f; unsigned u; } v; v.f = x;
  unsigned r = (v.u + 0x7FFFu + ((v.u >> 16) & 1u)) >> 16;
  return (short)r;
}
__device__ __forceinline__ float bf2f(short x) {
  union { unsigned u; float f; } v; v.u = ((unsigned)(unsigned short)x) << 16;
  return v.f;
}

// ------- bf16 copies (transposed+scaled, natural) + fused dot product ------
// in [b][ND][L] f32 -> outT [b][L][ND] bf16 (x wvec[d] if wvec),
//                      outN [b][ND][L] bf16 (if outN),
//                      dotv[b*L+i] += sum_dd in[b,d0+dd,i]*wdot[d0+dd].
__global__ __launch_bounds__(256) void k_tr(const float* __restrict__ in,
                                            const float* __restrict__ wvec,
                                            const float* __restrict__ wdot,
                                            short* __restrict__ outT,
                                            short* __restrict__ outN,
                                            float* __restrict__ dotv, int L) {
  __shared__ float T[32][66];
  const int b = blockIdx.z, d0 = blockIdx.y * 32, i0 = blockIdx.x * 64;
  const int t = threadIdx.x;
#pragma unroll
  for (int rr = 0; rr < 2; ++rr) {
    int idx = t + rr * 256;
    int dd = idx >> 4, c4 = idx & 15;
    const float* src = in + ((size_t)b * ND + d0 + dd) * L + i0 + c4 * 4;
    float4 v = *(const float4*)src;
    T[dd][c4 * 4 + 0] = v.x;
    T[dd][c4 * 4 + 1] = v.y;
    T[dd][c4 * 4 + 2] = v.z;
    T[dd][c4 * 4 + 3] = v.w;
    if (outN) {
      short4 o;
      o.x = f2bf(v.x); o.y = f2bf(v.y); o.z = f2bf(v.z); o.w = f2bf(v.w);
      *(short4*)(outN + ((size_t)b * ND + d0 + dd) * L + i0 + c4 * 4) = o;
    }
  }
  __syncthreads();
  // fused dot: threads 0-63 accumulate this d0-block's partial into dotv
  if (t < 64) {
    float s = 0.f;
#pragma unroll
    for (int dd = 0; dd < 32; ++dd) s = fmaf(T[dd][t], wdot[d0 + dd], s);
    atomicAdd(&dotv[(size_t)b * L + i0 + t], s);
  }
  const int i = t >> 2, seg = t & 3;
  bf16x8 pack;
#pragma unroll
  for (int k = 0; k < 8; ++k) {
    int d = seg * 8 + k;
    float x = T[d][i];
    if (wvec) x *= wvec[d0 + d];
    pack[k] = f2bf(x);
  }
  *(bf16x8*)(outT + ((size_t)b * L + i0 + i) * ND + d0 + seg * 8) = pack;
}

// ---------------- k_MT: MT[b,d,q] = sum_i softmax_col(S)[i,q] * C[b,d,i] ---
// grid (NLQ/16, NB), 512 thr (8 waves), QT=16. Single pass (const-shift exp).
// Wave w covers isub=w in the S^T phase and d-rows w*16..w*16+15 in MT GEMM.
__global__ __launch_bounds__(512) void k_MT(const short* __restrict__ Ctbf,
                                            const short* __restrict__ Qtw,
                                            const short* __restrict__ Cbf,
                                            const int* __restrict__ Cmask,
                                            const float* __restrict__ cq,
                                            const float* __restrict__ qq,
                                            const float* __restrict__ bias,
                                            short* __restrict__ MTbf) {
  __shared__ short PTs[16 * 136];   // P2^T bf16 [q 16][i-chunk 128], pad->136
  __shared__ float cspart[8][16];
  __shared__ float bc[16];
  const int b = blockIdx.y, qt = blockIdx.x * 16;
  const int tid = threadIdx.x;
  const int w = tid >> 6, l = tid & 63, lm = l & 15, lk = l >> 4;
  const float bv = bias[0];

  // A-frags (Q side), same 16 q-rows for all waves: A[m=q][k=d]
  bf16x8 aq[4];
  const short* Qrow = Qtw + ((size_t)b * NLQ + qt + lm) * ND + lk * 8;
#pragma unroll
  for (int kk = 0; kk < 4; ++kk) aq[kk] = *(const bf16x8*)(Qrow + kk * 32);
  float qqv[4];
#pragma unroll
  for (int r = 0; r < 4; ++r) qqv[r] = qq[b * NLQ + qt + lk * 4 + r];

  float csacc[4] = {0.f, 0.f, 0.f, 0.f};
  f32x4 accMT = {0.f, 0.f, 0.f, 0.f};
  for (int i0 = 0; i0 < NLC; i0 += 128) {
    // S^T tile [16 q x 128 i] via MFMA; wave w handles isub = w
    {
      const int iCol = i0 + w * 16 + lm;
      const short* Crow = Ctbf + ((size_t)b * NLC + iCol) * ND + lk * 8;
      f32x4 c = {0.f, 0.f, 0.f, 0.f};
#pragma unroll
      for (int kk = 0; kk < 4; ++kk)
        c = MFMA16(aq[kk], *(const bf16x8*)(Crow + kk * 32), c);
      const float cqb = cq[b * NLC + iCol] + bv;
      const int cm = Cmask[b * NLC + iCol];
#pragma unroll
      for (int r = 0; r < 4; ++r) {
        float s = c[r] + cqb + qqv[r];
        float v = cm ? s : s + FNEG;
        float p = __expf(v - ESHIFT);
        csacc[r] += p;
        PTs[(lk * 4 + r) * 136 + w * 16 + lm] = f2bf(p);
      }
    }
    __syncthreads();
    // MT GEMM: A[m=d]=Cbf (i-contig), B[k=i][n=q]=P^T from LDS
    const short* Arow = Cbf + ((size_t)b * ND + w * 16 + lm) * NLC + i0 + lk * 8;
#pragma unroll
    for (int ks = 0; ks < 4; ++ks) {
      bf16x8 a = *(const bf16x8*)(Arow + ks * 32);
      bf16x8 bb = *(const bf16x8*)&PTs[lm * 136 + ks * 32 + lk * 8];
      accMT = MFMA16(a, bb, accMT);
    }
    __syncthreads();
  }
  // colsum reduce: over i-lanes (lm) then over the 8 waves (isub portions)
#pragma unroll
  for (int off = 1; off < 16; off <<= 1)
#pragma unroll
    for (int r = 0; r < 4; ++r) csacc[r] += __shfl_xor(csacc[r], off, 64);
  if (lm == 0) {
#pragma unroll
    for (int r = 0; r < 4; ++r) cspart[w][lk * 4 + r] = csacc[r];
  }
  __syncthreads();
  if (tid < 16) {
    float s = 0.f;
#pragma unroll
    for (int k2 = 0; k2 < 8; ++k2) s += cspart[k2][tid];
    bc[tid] = 1.0f / s;
  }
  __syncthreads();
  const float inv = bc[lm];
#pragma unroll
  for (int r = 0; r < 4; ++r)
    MTbf[((size_t)b * ND + w * 16 + lk * 4 + r) * NLQ + qt + lm] =
        f2bf(accMT[r] * inv);
}

// ---------------- k_PAB: fused softmax + A/Bt GEMMs, LDS B-staging ---------
// (R12, unchanged.) 1D grid 1024 blocks (XCD-bijective swizzle). 256 thr.
__global__ __launch_bounds__(256) void k_PAB(const float* __restrict__ C,
                                             const short* __restrict__ Ctbf,
                                             const short* __restrict__ Qtw,
                                             const short* __restrict__ Qbf,
                                             const short* __restrict__ MTbf,
                                             const int* __restrict__ Qmask,
                                             const float* __restrict__ cq,
                                             const float* __restrict__ qq,
                                             const float* __restrict__ bias,
                                             float* __restrict__ out) {
  __shared__ __align__(16) char SMEM[64 * 264 * 2];  // PTs, then 2x16KB B-stage
  short* PTs = (short*)SMEM;
  char* Bst = SMEM;
  const int flat = blockIdx.x;                 // 1024 = 8*128 exactly
  const int swz = (flat & 7) * 128 + (flat >> 3);
  const int b = swz >> 5, it = (swz & 31) * 64;
  const int tid = threadIdx.x;
  const int wi = tid >> 6, l = tid & 63, lm = l & 15, lk = l >> 4;

  // ---- phase 1: S via MFMA -> exp -> LDS (raw p), rowsum in-register ----
  float invr[4];
  {
    bf16x8 aS[4];
    const short* Crow = Ctbf + ((size_t)b * NLC + it + wi * 16 + lm) * ND + lk * 8;
#pragma unroll
    for (int kk = 0; kk < 4; ++kk) aS[kk] = *(const bf16x8*)(Crow + kk * 32);
    const float bv = bias[0];
    float cqb[4];
#pragma unroll
    for (int r = 0; r < 4; ++r) cqb[r] = cq[b * NLC + it + wi * 16 + lk * 4 + r] + bv;
    const short* Qt0 = Qtw + (size_t)b * NLQ * ND;

    float rsum[4] = {0.f, 0.f, 0.f, 0.f};
#pragma unroll
    for (int js = 0; js < 16; ++js) {
      const short* Qrow = Qt0 + (size_t)(js * 16 + lm) * ND + lk * 8;
      f32x4 c = {0.f, 0.f, 0.f, 0.f};
#pragma unroll
      for (int kk = 0; kk < 4; ++kk)
        c = MFMA16(aS[kk], *(const bf16x8*)(Qrow + kk * 32), c);
      const int j = js * 16 + lm;
      const float qv = qq[b * NLQ + j];
      const int qm = Qmask[b * NLQ + j];
#pragma unroll
      for (int r = 0; r < 4; ++r) {
        float s = c[r] + cqb[r] + qv;
        float v = qm ? s : s + FNEG;
        float p = __expf(v - ESHIFT);
        rsum[r] += p;
        PTs[(wi * 16 + lk * 4 + r) * 264 + js * 16 + lm] = f2bf(p);
      }
    }
#pragma unroll
    for (int off = 1; off < 16; off <<= 1)
#pragma unroll
      for (int r = 0; r < 4; ++r) rsum[r] += __shfl_xor(rsum[r], off, 64);
#pragma unroll
    for (int r = 0; r < 4; ++r) invr[r] = 1.0f / rsum[r];
  }
  __syncthreads();

  // ---- afr (raw p rows) from PTs ----
  bf16x8 afr[8];
#pragma unroll
  for (int kk = 0; kk < 8; ++kk)
    afr[kk] = *(const bf16x8*)&PTs[(wi * 16 + lm) * 264 + kk * 32 + lk * 8];
  __syncthreads();  // all PTs reads done before B-staging overwrite

  // ---- phase 2: double-buffered B-panel staging + MFMA + direct stores ----
  const short* Qp = Qbf + (size_t)b * ND * NLQ;
  const short* Mp = MTbf + (size_t)b * ND * NLQ;
  const float* Cb = C + (size_t)b * ND * NLC;
  float* ob = out + (size_t)b * 4 * ND * NLC;
  const int iB = it + wi * 16 + lk * 4;

  // staging thread mapping: 16 rows x 16 cols of 32B (per panel, 8KB)
  const int srow = tid >> 4, scol = tid & 15;
  const int wsw0 = (((scol * 2) ^ (srow & 7)) << 4);
  const int wsw1 = (((scol * 2 + 1) ^ (srow & 7)) << 4);
  const short* qsrc = Qp + (size_t)srow * NLQ + scol * 16;
  const short* msrc = Mp + (size_t)srow * NLQ + scol * 16;
  bf16x8 sq0, sq1, sm0, sm1;

#define LOADN(n0) { \
    const short* q_ = qsrc + (size_t)(n0) * 16 * NLQ; \
    const short* m_ = msrc + (size_t)(n0) * 16 * NLQ; \
    sq0 = *(const bf16x8*)q_;  sq1 = *(const bf16x8*)(q_ + 8); \
    sm0 = *(const bf16x8*)m_;  sm1 = *(const bf16x8*)(m_ + 8); }
#define WRITEN(buf) { \
    char* base_ = Bst + (buf) * 16384 + srow * 512; \
    *(bf16x8*)(base_ + wsw0) = sq0; *(bf16x8*)(base_ + wsw1) = sq1; \
    *(bf16x8*)(base_ + 8192 + wsw0) = sm0; *(bf16x8*)(base_ + 8192 + wsw1) = sm1; }

  LOADN(0); WRITEN(0);
  __syncthreads();
#pragma unroll
  for (int n0 = 0; n0 < 8; ++n0) {
    if (n0 < 7) LOADN(n0 + 1);                 // issue next-tile loads early
    const int d = n0 * 16 + lm;
    float4 ct = *(const float4*)&Cb[(size_t)d * NLC + iB];  // independent, early
    const char* bq = Bst + (n0 & 1) * 16384 + lm * 512;
    f32x4 cA = {0.f, 0.f, 0.f, 0.f};
    f32x4 cB = {0.f, 0.f, 0.f, 0.f};
#pragma unroll
    for (int kk = 0; kk < 8; ++kk) {
      const int so = (((kk * 4 + lk) ^ (lm & 7)) << 4);
      cA = MFMA16(afr[kk], *(const bf16x8*)(bq + so), cA);
      cB = MFMA16(afr[kk], *(const bf16x8*)(bq + 8192 + so), cB);
    }
    if (n0 < 7) {
      WRITEN((n0 + 1) & 1);                    // write-late into other buffer
      __syncthreads();
    }
    float4 av, ca, cb;
    av.x = cA[0] * invr[0]; av.y = cA[1] * invr[1];
    av.z = cA[2] * invr[2]; av.w = cA[3] * invr[3];
    ca.x = ct.x * av.x; ca.y = ct.y * av.y; ca.z = ct.z * av.z; ca.w = ct.w * av.w;
    cb.x = ct.x * cB[0] * invr[0]; cb.y = ct.y * cB[1] * invr[1];
    cb.z = ct.z * cB[2] * invr[2]; cb.w = ct.w * cB[3] * invr[3];
    float* o0 = ob + (size_t)d * NLC + iB;
    *(float4*)o0 = ct;
    *(float4*)(o0 + (size_t)128 * NLC) = av;
    *(float4*)(o0 + (size_t)256 * NLC) = ca;
    *(float4*)(o0 + (size_t)384 * NLC) = cb;
  }
#undef LOADN
#undef WRITEN
}

// ---------------------------------------------------------------------------
extern "C" void kernel_launch(void* const* d_in, const int* in_sizes, int n_in,
                              void* d_out, int out_size, void* d_ws, size_t ws_size,
                              hipStream_t stream) {
  const float* C = (const float*)d_in[0];
  const float* Q = (const float*)d_in[1];
  const int* Cmask = (const int*)d_in[2];
  const int* Qmask = (const int*)d_in[3];
  const float* w4C = (const float*)d_in[4];
  const float* w4Q = (const float*)d_in[5];
  const float* w4mlu = (const float*)d_in[6];
  const float* bias = (const float*)d_in[7];
  float* out = (float*)d_out;

  short* Ctbf = (short*)d_ws;                          // [b][Lc][D]
  short* Cbf = Ctbf + (size_t)NB * NLC * ND;           // [b][D][Lc]
  short* Qtw = Cbf + (size_t)NB * NLC * ND;            // [b][Lq][D] (w4mlu folded)
  short* Qbf = Qtw + (size_t)NB * NLQ * ND;            // [b][D][Lq]
  short* MTbf = Qbf + (size_t)NB * NLQ * ND;           // [b][D][Lq]
  float* cq = (float*)(MTbf + (size_t)NB * ND * NLQ);
  float* qq = cq + NB * NLC;
  size_t need = (size_t)(qq + NB * NLQ - (float*)d_ws) * sizeof(float);
  if (ws_size < need) return;  // fail loudly rather than corrupt

  hipMemsetAsync(cq, 0, (size_t)(NB * NLC + NB * NLQ) * sizeof(float), stream);
  k_tr<<<dim3(NLC / 64, ND / 32, NB), 256, 0, stream>>>(C, nullptr, w4C, Ctbf, Cbf, cq, NLC);
  k_tr<<<dim3(NLQ / 64, ND / 32, NB), 256, 0, stream>>>(Q, w4mlu, w4Q, Qtw, Qbf, qq, NLQ);
  k_MT<<<dim3(NLQ / 16, NB), 512, 0, stream>>>(Ctbf, Qtw, Cbf, Cmask, cq, qq, bias, MTbf);
  k_PAB<<<1024, 256, 0, stream>>>(C, Ctbf, Qtw, Qbf, MTbf, Qmask, cq, qq, bias, out);
}

// Round 14
// 137.634 us; speedup vs baseline: 1.0907x; 1.0907x over previous
//
#include <hip/hip_runtime.h>
#include <cstdint>

// CQAttention: B=32, D=128, Lc=2048, Lq=256, f32 in/out.
// Pipeline (R14):
//   memset  : zero cq/qq accumulators (260KB)
//   k_tr x2 : bf16 copies + fused dot products (R13): Ct_bf [b][i][d],
//             Cbf [b][d][i], cq += C.w4C partials; Qtw [b][j][d] (w4mlu
//             folded), Qbf [b][d][j], qq += Q.w4Q.
//   k_MT    : QT=32 (R12-proven shape; R13's QT=16 doubled L2 streaming -
//             reverted). R14: XCD-bijective swizzle, XCD k owns batches
//             4k..4k+3 (4MB working set = its L2). Single pass exp(v-20):
//             S^T via MFMA -> LDS P^T -> MT = C@P2 / colsum -> bf16.
//   k_PAB   : fused row-softmax + A/Bt GEMMs with double-buffered LDS
//             B-panel staging (R12, proven). R14: Ct epilogue stream read
//             from Cbf bf16 (halves the 64MB f32 C read; f32 C no longer
//             an input). Output Ct is bf16-rounded (err << threshold).
// Bt = S1 @ (S2^T @ Ct) associativity rewrite avoids the Lc x Lc matrix.

#define NB 32
#define ND 128
#define NLC 2048
#define NLQ 256
#define FNEG (-1.0e30f)
#define ESHIFT 20.0f

typedef __attribute__((ext_vector_type(8))) short bf16x8;
typedef __attribute__((ext_vector_type(4))) float f32x4;
#define MFMA16(a, b, c) __builtin_amdgcn_mfma_f32_16x16x32_bf16(a, b, c, 0, 0, 0)

__device__ __forceinline__ short f2bf(float x) {
  union { float f; unsigned u; } v; v.f = x;
  unsigned r = (v.u + 0x7FFFu + ((v.u >> 16) & 1u)) >> 16;
  return (short)r;
}
__device__ __forceinline__ float bf2f(short x) {
  union { unsigned u; float f; } v; v.u = ((unsigned)(unsigned short)x) << 16;
  return v.f;
}

// ------- bf16 copies (transposed+scaled, natural) + fused dot product ------
__global__ __launch_bounds__(256) void k_tr(const float* __restrict__ in,
                                            const float* __restrict__ wvec,
                                            const float* __restrict__ wdot,
                                            short* __restrict__ outT,
                                            short* __restrict__ outN,
                                            float* __restrict__ dotv, int L) {
  __shared__ float T[32][66];
  const int b = blockIdx.z, d0 = blockIdx.y * 32, i0 = blockIdx.x * 64;
  const int t = threadIdx.x;
#pragma unroll
  for (int rr = 0; rr < 2; ++rr) {
    int idx = t + rr * 256;
    int dd = idx >> 4, c4 = idx & 15;
    const float* src = in + ((size_t)b * ND + d0 + dd) * L + i0 + c4 * 4;
    float4 v = *(const float4*)src;
    T[dd][c4 * 4 + 0] = v.x;
    T[dd][c4 * 4 + 1] = v.y;
    T[dd][c4 * 4 + 2] = v.z;
    T[dd][c4 * 4 + 3] = v.w;
    if (outN) {
      short4 o;
      o.x = f2bf(v.x); o.y = f2bf(v.y); o.z = f2bf(v.z); o.w = f2bf(v.w);
      *(short4*)(outN + ((size_t)b * ND + d0 + dd) * L + i0 + c4 * 4) = o;
    }
  }
  __syncthreads();
  // fused dot: threads 0-63 accumulate this d0-block's partial into dotv
  if (t < 64) {
    float s = 0.f;
#pragma unroll
    for (int dd = 0; dd < 32; ++dd) s = fmaf(T[dd][t], wdot[d0 + dd], s);
    atomicAdd(&dotv[(size_t)b * L + i0 + t], s);
  }
  const int i = t >> 2, seg = t & 3;
  bf16x8 pack;
#pragma unroll
  for (int k = 0; k < 8; ++k) {
    int d = seg * 8 + k;
    float x = T[d][i];
    if (wvec) x *= wvec[d0 + d];
    pack[k] = f2bf(x);
  }
  *(bf16x8*)(outT + ((size_t)b * L + i0 + i) * ND + d0 + seg * 8) = pack;
}

// ---------------- k_MT: MT[b,d,q] = sum_i softmax_col(S)[i,q] * C[b,d,i] ---
// 1D grid 256 blocks (8 XCD x 32: XCD k -> batches 4k..4k+3), 512 thr.
// QT=32. Single pass (const-shift exp). R12-proven inner structure.
__global__ __launch_bounds__(512) void k_MT(const short* __restrict__ Ctbf,
                                            const short* __restrict__ Qtw,
                                            const short* __restrict__ Cbf,
                                            const int* __restrict__ Cmask,
                                            const float* __restrict__ cq,
                                            const float* __restrict__ qq,
                                            const float* __restrict__ bias,
                                            short* __restrict__ MTbf) {
  __shared__ short PTs[32 * 136];   // P2^T bf16 [q 32][i-chunk 128], pad->136
  __shared__ float cspart[8][32];
  __shared__ float bc[32];
  const int flat = blockIdx.x;                 // 256 = 8*32 exactly
  const int swz = (flat & 7) * 32 + (flat >> 3);
  const int b = swz >> 3, qt = (swz & 7) * 32;
  const int tid = threadIdx.x;
  const int w = tid >> 6, l = tid & 63, lm = l & 15, lk = l >> 4;
  const int qsub = w & 1, ipair = w >> 1;
  const float bv = bias[0];

  bf16x8 aq[4];
  const short* Qrow = Qtw + ((size_t)b * NLQ + qt + qsub * 16 + lm) * ND + lk * 8;
#pragma unroll
  for (int kk = 0; kk < 4; ++kk) aq[kk] = *(const bf16x8*)(Qrow + kk * 32);
  float qqv[4];
#pragma unroll
  for (int r = 0; r < 4; ++r) qqv[r] = qq[b * NLQ + qt + qsub * 16 + lk * 4 + r];

  float csacc[4] = {0.f, 0.f, 0.f, 0.f};
  f32x4 accMT[2] = {{0.f, 0.f, 0.f, 0.f}, {0.f, 0.f, 0.f, 0.f}};
  for (int i0 = 0; i0 < NLC; i0 += 128) {
#pragma unroll
    for (int t2 = 0; t2 < 2; ++t2) {
      const int isub = ipair * 2 + t2;
      const int iCol = i0 + isub * 16 + lm;
      const short* Crow = Ctbf + ((size_t)b * NLC + iCol) * ND + lk * 8;
      f32x4 c = {0.f, 0.f, 0.f, 0.f};
#pragma unroll
      for (int kk = 0; kk < 4; ++kk)
        c = MFMA16(aq[kk], *(const bf16x8*)(Crow + kk * 32), c);
      const float cqb = cq[b * NLC + iCol] + bv;
      const int cm = Cmask[b * NLC + iCol];
#pragma unroll
      for (int r = 0; r < 4; ++r) {
        float s = c[r] + cqb + qqv[r];
        float v = cm ? s : s + FNEG;
        float p = __expf(v - ESHIFT);
        csacc[r] += p;
        PTs[(qsub * 16 + lk * 4 + r) * 136 + isub * 16 + lm] = f2bf(p);
      }
    }
    __syncthreads();
    // MT GEMM: A[m=d]=Cbf (i-contig), B[k=i][n=q]=P^T from LDS
    const short* Arow = Cbf + ((size_t)b * ND + w * 16 + lm) * NLC + i0 + lk * 8;
#pragma unroll
    for (int ks = 0; ks < 4; ++ks) {
      bf16x8 a = *(const bf16x8*)(Arow + ks * 32);
#pragma unroll
      for (int qs = 0; qs < 2; ++qs) {
        bf16x8 bb = *(const bf16x8*)&PTs[(qs * 16 + lm) * 136 + ks * 32 + lk * 8];
        accMT[qs] = MFMA16(a, bb, accMT[qs]);
      }
    }
    __syncthreads();
  }
  // colsum reduce
#pragma unroll
  for (int off = 1; off < 16; off <<= 1)
#pragma unroll
    for (int r = 0; r < 4; ++r) csacc[r] += __shfl_xor(csacc[r], off, 64);
  if (lm == 0) {
#pragma unroll
    for (int r = 0; r < 4; ++r) cspart[w][qsub * 16 + lk * 4 + r] = csacc[r];
  }
  __syncthreads();
  if (tid < 32) {
    const int base = (tid >> 4) & 1;
    float s = 0.f;
#pragma unroll
    for (int k2 = 0; k2 < 4; ++k2) s += cspart[k2 * 2 + base][tid];
    bc[tid] = 1.0f / s;
  }
  __syncthreads();
#pragma unroll
  for (int qs = 0; qs < 2; ++qs) {
    const float inv = bc[qs * 16 + lm];
#pragma unroll
    for (int r = 0; r < 4; ++r)
      MTbf[((size_t)b * ND + w * 16 + lk * 4 + r) * NLQ + qt + qs * 16 + lm] =
          f2bf(accMT[qs][r] * inv);
  }
}

// ---------------- k_PAB: fused softmax + A/Bt GEMMs, LDS B-staging ---------
// 1D grid 1024 blocks (XCD-bijective swizzle). 256 thr (4 waves).
// R14: ct stream read from Cbf (bf16) - f32 C input dropped.
__global__ __launch_bounds__(256) void k_PAB(const short* __restrict__ Cbf,
                                             const short* __restrict__ Ctbf,
                                             const short* __restrict__ Qtw,
                                             const short* __restrict__ Qbf,
                                             const short* __restrict__ MTbf,
                                             const int* __restrict__ Qmask,
                                             const float* __restrict__ cq,
                                             const float* __restrict__ qq,
                                             const float* __restrict__ bias,
                                             float* __restrict__ out) {
  __shared__ __align__(16) char SMEM[64 * 264 * 2];  // PTs, then 2x16KB B-stage
  short* PTs = (short*)SMEM;
  char* Bst = SMEM;
  const int flat = blockIdx.x;                 // 1024 = 8*128 exactly
  const int swz = (flat & 7) * 128 + (flat >> 3);
  const int b = swz >> 5, it = (swz & 31) * 64;
  const int tid = threadIdx.x;
  const int wi = tid >> 6, l = tid & 63, lm = l & 15, lk = l >> 4;

  // ---- phase 1: S via MFMA -> exp -> LDS (raw p), rowsum in-register ----
  float invr[4];
  {
    bf16x8 aS[4];
    const short* Crow = Ctbf + ((size_t)b * NLC + it + wi * 16 + lm) * ND + lk * 8;
#pragma unroll
    for (int kk = 0; kk < 4; ++kk) aS[kk] = *(const bf16x8*)(Crow + kk * 32);
    const float bv = bias[0];
    float cqb[4];
#pragma unroll
    for (int r = 0; r < 4; ++r) cqb[r] = cq[b * NLC + it + wi * 16 + lk * 4 + r] + bv;
    const short* Qt0 = Qtw + (size_t)b * NLQ * ND;

    float rsum[4] = {0.f, 0.f, 0.f, 0.f};
#pragma unroll
    for (int js = 0; js < 16; ++js) {
      const short* Qrow = Qt0 + (size_t)(js * 16 + lm) * ND + lk * 8;
      f32x4 c = {0.f, 0.f, 0.f, 0.f};
#pragma unroll
      for (int kk = 0; kk < 4; ++kk)
        c = MFMA16(aS[kk], *(const bf16x8*)(Qrow + kk * 32), c);
      const int j = js * 16 + lm;
      const float qv = qq[b * NLQ + j];
      const int qm = Qmask[b * NLQ + j];
#pragma unroll
      for (int r = 0; r < 4; ++r) {
        float s = c[r] + cqb[r] + qv;
        float v = qm ? s : s + FNEG;
        float p = __expf(v - ESHIFT);
        rsum[r] += p;
        PTs[(wi * 16 + lk * 4 + r) * 264 + js * 16 + lm] = f2bf(p);
      }
    }
#pragma unroll
    for (int off = 1; off < 16; off <<= 1)
#pragma unroll
      for (int r = 0; r < 4; ++r) rsum[r] += __shfl_xor(rsum[r], off, 64);
#pragma unroll
    for (int r = 0; r < 4; ++r) invr[r] = 1.0f / rsum[r];
  }
  __syncthreads();

  // ---- afr (raw p rows) from PTs ----
  bf16x8 afr[8];
#pragma unroll
  for (int kk = 0; kk < 8; ++kk)
    afr[kk] = *(const bf16x8*)&PTs[(wi * 16 + lm) * 264 + kk * 32 + lk * 8];
  __syncthreads();  // all PTs reads done before B-staging overwrite

  // ---- phase 2: double-buffered B-panel staging + MFMA + direct stores ----
  const short* Qp = Qbf + (size_t)b * ND * NLQ;
  const short* Mp = MTbf + (size_t)b * ND * NLQ;
  const short* Cb = Cbf + (size_t)b * ND * NLC;
  float* ob = out + (size_t)b * 4 * ND * NLC;
  const int iB = it + wi * 16 + lk * 4;

  // staging thread mapping: 16 rows x 16 cols of 32B (per panel, 8KB)
  const int srow = tid >> 4, scol = tid & 15;
  const int wsw0 = (((scol * 2) ^ (srow & 7)) << 4);
  const int wsw1 = (((scol * 2 + 1) ^ (srow & 7)) << 4);
  const short* qsrc = Qp + (size_t)srow * NLQ + scol * 16;
  const short* msrc = Mp + (size_t)srow * NLQ + scol * 16;
  bf16x8 sq0, sq1, sm0, sm1;

#define LOADN(n0) { \
    const short* q_ = qsrc + (size_t)(n0) * 16 * NLQ; \
    const short* m_ = msrc + (size_t)(n0) * 16 * NLQ; \
    sq0 = *(const bf16x8*)q_;  sq1 = *(const bf16x8*)(q_ + 8); \
    sm0 = *(const bf16x8*)m_;  sm1 = *(const bf16x8*)(m_ + 8); }
#define WRITEN(buf) { \
    char* base_ = Bst + (buf) * 16384 + srow * 512; \
    *(bf16x8*)(base_ + wsw0) = sq0; *(bf16x8*)(base_ + wsw1) = sq1; \
    *(bf16x8*)(base_ + 8192 + wsw0) = sm0; *(bf16x8*)(base_ + 8192 + wsw1) = sm1; }

  LOADN(0); WRITEN(0);
  __syncthreads();
#pragma unroll
  for (int n0 = 0; n0 < 8; ++n0) {
    if (n0 < 7) LOADN(n0 + 1);                 // issue next-tile loads early
    const int d = n0 * 16 + lm;
    short4 cts = *(const short4*)&Cb[(size_t)d * NLC + iB];  // bf16 ct, early
    const char* bq = Bst + (n0 & 1) * 16384 + lm * 512;
    f32x4 cA = {0.f, 0.f, 0.f, 0.f};
    f32x4 cB = {0.f, 0.f, 0.f, 0.f};
#pragma unroll
    for (int kk = 0; kk < 8; ++kk) {
      const int so = (((kk * 4 + lk) ^ (lm & 7)) << 4);
      cA = MFMA16(afr[kk], *(const bf16x8*)(bq + so), cA);
      cB = MFMA16(afr[kk], *(const bf16x8*)(bq + 8192 + so), cB);
    }
    if (n0 < 7) {
      WRITEN((n0 + 1) & 1);                    // write-late into other buffer
      __syncthreads();
    }
    float4 ct;
    ct.x = bf2f(cts.x); ct.y = bf2f(cts.y); ct.z = bf2f(cts.z); ct.w = bf2f(cts.w);
    float4 av, ca, cb;
    av.x = cA[0] * invr[0]; av.y = cA[1] * invr[1];
    av.z = cA[2] * invr[2]; av.w = cA[3] * invr[3];
    ca.x = ct.x * av.x; ca.y = ct.y * av.y; ca.z = ct.z * av.z; ca.w = ct.w * av.w;
    cb.x = ct.x * cB[0] * invr[0]; cb.y = ct.y * cB[1] * invr[1];
    cb.z = ct.z * cB[2] * invr[2]; cb.w = ct.w * cB[3] * invr[3];
    float* o0 = ob + (size_t)d * NLC + iB;
    *(float4*)o0 = ct;
    *(float4*)(o0 + (size_t)128 * NLC) = av;
    *(float4*)(o0 + (size_t)256 * NLC) = ca;
    *(float4*)(o0 + (size_t)384 * NLC) = cb;
  }
#undef LOADN
#undef WRITEN
}

// ---------------------------------------------------------------------------
extern "C" void kernel_launch(void* const* d_in, const int* in_sizes, int n_in,
                              void* d_out, int out_size, void* d_ws, size_t ws_size,
                              hipStream_t stream) {
  const float* C = (const float*)d_in[0];
  const float* Q = (const float*)d_in[1];
  const int* Cmask = (const int*)d_in[2];
  const int* Qmask = (const int*)d_in[3];
  const float* w4C = (const float*)d_in[4];
  const float* w4Q = (const float*)d_in[5];
  const float* w4mlu = (const float*)d_in[6];
  const float* bias = (const float*)d_in[7];
  float* out = (float*)d_out;

  short* Ctbf = (short*)d_ws;                          // [b][Lc][D]
  short* Cbf = Ctbf + (size_t)NB * NLC * ND;           // [b][D][Lc]
  short* Qtw = Cbf + (size_t)NB * NLC * ND;            // [b][Lq][D] (w4mlu folded)
  short* Qbf = Qtw + (size_t)NB * NLQ * ND;            // [b][D][Lq]
  short* MTbf = Qbf + (size_t)NB * NLQ * ND;           // [b][D][Lq]
  float* cq = (float*)(MTbf + (size_t)NB * ND * NLQ);
  float* qq = cq + NB * NLC;
  size_t need = (size_t)(qq + NB * NLQ - (float*)d_ws) * sizeof(float);
  if (ws_size < need) return;  // fail loudly rather than corrupt

  hipMemsetAsync(cq, 0, (size_t)(NB * NLC + NB * NLQ) * sizeof(float), stream);
  k_tr<<<dim3(NLC / 64, ND / 32, NB), 256, 0, stream>>>(C, nullptr, w4C, Ctbf, Cbf, cq, NLC);
  k_tr<<<dim3(NLQ / 64, ND / 32, NB), 256, 0, stream>>>(Q, w4mlu, w4Q, Qtw, Qbf, qq, NLQ);
  k_MT<<<256, 512, 0, stream>>>(Ctbf, Qtw, Cbf, Cmask, cq, qq, bias, MTbf);
  k_PAB<<<1024, 256, 0, stream>>>(Cbf, Ctbf, Qtw, Qbf, MTbf, Qmask, cq, qq, bias, out);
}

// Round 15
// 115.647 us; speedup vs baseline: 1.2981x; 1.1901x over previous
//
#include <hip/hip_runtime.h>
#include <cstdint>

// CQAttention: B=32, D=128, Lc=2048, Lq=256, f32 in/out.
// Pipeline (R15):
//   memset  : zero cq/qq accumulators (260KB)
//   k_tr x2 : bf16 copies + fused dot products. R15: transposed outputs are
//             written FRAGMENT-MAJOR: arr[b][tile=j>>4][kk=d>>5][lane][8]
//             (1KB per (tile,kk); lane l at l*16B). All MFMA A/B fragment
//             consumers then load one contiguous 1KB per wave instruction
//             instead of 16 scattered 64B segments (the R12 lesson, applied
//             via pre-swizzled global layout instead of LDS).
//             Also: Cbf [b][d][i] natural copy, cq/qq fused dots.
//   k_MT    : QT=32, XCD-bijective swizzle (R14). aq + Ct fragment loads
//             now fragment-major (R15). Single pass exp(v-20).
//   k_PAB   : fused row-softmax + A/Bt GEMMs, double-buffered LDS B-panel
//             staging (R12), bf16 ct stream (R14). R15: phase-1 aS + Q
//             fragment loads fragment-major.
// Bt = S1 @ (S2^T @ Ct) associativity rewrite avoids the Lc x Lc matrix.

#define NB 32
#define ND 128
#define NLC 2048
#define NLQ 256
#define FNEG (-1.0e30f)
#define ESHIFT 20.0f

typedef __attribute__((ext_vector_type(8))) short bf16x8;
typedef __attribute__((ext_vector_type(4))) float f32x4;
#define MFMA16(a, b, c) __builtin_amdgcn_mfma_f32_16x16x32_bf16(a, b, c, 0, 0, 0)

__device__ __forceinline__ short f2bf(float x) {
  union { float f; unsigned u; } v; v.f = x;
  unsigned r = (v.u + 0x7FFFu + ((v.u >> 16) & 1u)) >> 16;
  return (short)r;
}
__device__ __forceinline__ float bf2f(short x) {
  union { unsigned u; float f; } v; v.u = ((unsigned)(unsigned short)x) << 16;
  return v.f;
}

// ------- bf16 copies (fragment-major transposed + natural) + fused dot -----
// in [b][ND][L] f32 ->
//   outT fragment-major: [b][L/16 tiles][4 kk][64 lanes][8 bf16] (x wvec[d])
//   outN [b][ND][L] bf16 (if outN)
//   dotv[b*L+i] += sum_dd in[b,d0+dd,i]*wdot[d0+dd]
__global__ __launch_bounds__(256) void k_tr(const float* __restrict__ in,
                                            const float* __restrict__ wvec,
                                            const float* __restrict__ wdot,
                                            short* __restrict__ outT,
                                            short* __restrict__ outN,
                                            float* __restrict__ dotv, int L) {
  __shared__ float T[32][66];
  const int b = blockIdx.z, d0 = blockIdx.y * 32, i0 = blockIdx.x * 64;
  const int t = threadIdx.x;
#pragma unroll
  for (int rr = 0; rr < 2; ++rr) {
    int idx = t + rr * 256;
    int dd = idx >> 4, c4 = idx & 15;
    const float* src = in + ((size_t)b * ND + d0 + dd) * L + i0 + c4 * 4;
    float4 v = *(const float4*)src;
    T[dd][c4 * 4 + 0] = v.x;
    T[dd][c4 * 4 + 1] = v.y;
    T[dd][c4 * 4 + 2] = v.z;
    T[dd][c4 * 4 + 3] = v.w;
    if (outN) {
      short4 o;
      o.x = f2bf(v.x); o.y = f2bf(v.y); o.z = f2bf(v.z); o.w = f2bf(v.w);
      *(short4*)(outN + ((size_t)b * ND + d0 + dd) * L + i0 + c4 * 4) = o;
    }
  }
  __syncthreads();
  // fused dot: threads 0-63 accumulate this d0-block's partial into dotv
  if (t < 64) {
    float s = 0.f;
#pragma unroll
    for (int dd = 0; dd < 32; ++dd) s = fmaf(T[dd][t], wdot[d0 + dd], s);
    atomicAdd(&dotv[(size_t)b * L + i0 + t], s);
  }
  const int i = t >> 2, seg = t & 3;
  bf16x8 pack;
#pragma unroll
  for (int k = 0; k < 8; ++k) {
    int d = seg * 8 + k;
    float x = T[d][i];
    if (wvec) x *= wvec[d0 + d];
    pack[k] = f2bf(x);
  }
  // fragment-major store: tile=(i0+i)>>4, kk=d0>>5, lane=seg*16+((i0+i)&15)
  {
    const size_t tile = (size_t)((i0 + i) >> 4);
    const int lane = seg * 16 + ((i0 + i) & 15);
    *(bf16x8*)(outT + ((size_t)b * (L >> 4) + tile) * 2048 +
               (size_t)(d0 >> 5) * 512 + (size_t)lane * 8) = pack;
  }
}

// ---------------- k_MT: MT[b,d,q] = sum_i softmax_col(S)[i,q] * C[b,d,i] ---
// 1D grid 256 blocks (8 XCD x 32: XCD k -> batches 4k..4k+3), 512 thr.
// QT=32. Fragment-major aq/Ct loads (R15). Single pass (const-shift exp).
__global__ __launch_bounds__(512) void k_MT(const short* __restrict__ Cfr,
                                            const short* __restrict__ Qfr,
                                            const short* __restrict__ Cbf,
                                            const int* __restrict__ Cmask,
                                            const float* __restrict__ cq,
                                            const float* __restrict__ qq,
                                            const float* __restrict__ bias,
                                            short* __restrict__ MTbf) {
  __shared__ short PTs[32 * 136];   // P2^T bf16 [q 32][i-chunk 128], pad->136
  __shared__ float cspart[8][32];
  __shared__ float bc[32];
  const int flat = blockIdx.x;                 // 256 = 8*32 exactly
  const int swz = (flat & 7) * 32 + (flat >> 3);
  const int b = swz >> 3, qt = (swz & 7) * 32;
  const int tid = threadIdx.x;
  const int w = tid >> 6, l = tid & 63, lm = l & 15, lk = l >> 4;
  const int qsub = w & 1, ipair = w >> 1;
  const float bv = bias[0];

  // fragment-major aq: tileJ = qt/16 + qsub
  bf16x8 aq[4];
  {
    const short* Qf = Qfr + ((size_t)b * 16 + (qt >> 4) + qsub) * 2048 + (size_t)l * 8;
#pragma unroll
    for (int kk = 0; kk < 4; ++kk) aq[kk] = *(const bf16x8*)(Qf + kk * 512);
  }
  float qqv[4];
#pragma unroll
  for (int r = 0; r < 4; ++r) qqv[r] = qq[b * NLQ + qt + qsub * 16 + lk * 4 + r];

  float csacc[4] = {0.f, 0.f, 0.f, 0.f};
  f32x4 accMT[2] = {{0.f, 0.f, 0.f, 0.f}, {0.f, 0.f, 0.f, 0.f}};
  for (int i0 = 0; i0 < NLC; i0 += 128) {
#pragma unroll
    for (int t2 = 0; t2 < 2; ++t2) {
      const int isub = ipair * 2 + t2;
      const int iCol = i0 + isub * 16 + lm;
      // fragment-major Ct tile: tileI = i0/16 + isub
      const short* Cf = Cfr + ((size_t)b * 128 + (i0 >> 4) + isub) * 2048 + (size_t)l * 8;
      f32x4 c = {0.f, 0.f, 0.f, 0.f};
#pragma unroll
      for (int kk = 0; kk < 4; ++kk)
        c = MFMA16(aq[kk], *(const bf16x8*)(Cf + kk * 512), c);
      const float cqb = cq[b * NLC + iCol] + bv;
      const int cm = Cmask[b * NLC + iCol];
#pragma unroll
      for (int r = 0; r < 4; ++r) {
        float s = c[r] + cqb + qqv[r];
        float v = cm ? s : s + FNEG;
        float p = __expf(v - ESHIFT);
        csacc[r] += p;
        PTs[(qsub * 16 + lk * 4 + r) * 136 + isub * 16 + lm] = f2bf(p);
      }
    }
    __syncthreads();
    // MT GEMM: A[m=d]=Cbf (i-contig), B[k=i][n=q]=P^T from LDS
    const short* Arow = Cbf + ((size_t)b * ND + w * 16 + lm) * NLC + i0 + lk * 8;
#pragma unroll
    for (int ks = 0; ks < 4; ++ks) {
      bf16x8 a = *(const bf16x8*)(Arow + ks * 32);
#pragma unroll
      for (int qs = 0; qs < 2; ++qs) {
        bf16x8 bb = *(const bf16x8*)&PTs[(qs * 16 + lm) * 136 + ks * 32 + lk * 8];
        accMT[qs] = MFMA16(a, bb, accMT[qs]);
      }
    }
    __syncthreads();
  }
  // colsum reduce
#pragma unroll
  for (int off = 1; off < 16; off <<= 1)
#pragma unroll
    for (int r = 0; r < 4; ++r) csacc[r] += __shfl_xor(csacc[r], off, 64);
  if (lm == 0) {
#pragma unroll
    for (int r = 0; r < 4; ++r) cspart[w][qsub * 16 + lk * 4 + r] = csacc[r];
  }
  __syncthreads();
  if (tid < 32) {
    const int base = (tid >> 4) & 1;
    float s = 0.f;
#pragma unroll
    for (int k2 = 0; k2 < 4; ++k2) s += cspart[k2 * 2 + base][tid];
    bc[tid] = 1.0f / s;
  }
  __syncthreads();
#pragma unroll
  for (int qs = 0; qs < 2; ++qs) {
    const float inv = bc[qs * 16 + lm];
#pragma unroll
    for (int r = 0; r < 4; ++r)
      MTbf[((size_t)b * ND + w * 16 + lk * 4 + r) * NLQ + qt + qs * 16 + lm] =
          f2bf(accMT[qs][r] * inv);
  }
}

// ---------------- k_PAB: fused softmax + A/Bt GEMMs, LDS B-staging ---------
// 1D grid 1024 blocks (XCD-bijective swizzle). 256 thr (4 waves).
// Phase 1 (R15): aS + Q fragment loads fragment-major (1KB/wave-instr).
// Phase 2: double-buffered B-panel staging (R12), bf16 ct stream (R14).
__global__ __launch_bounds__(256) void k_PAB(const short* __restrict__ Cbf,
                                             const short* __restrict__ Cfr,
                                             const short* __restrict__ Qfr,
                                             const short* __restrict__ Qbf,
                                             const short* __restrict__ MTbf,
                                             const int* __restrict__ Qmask,
                                             const float* __restrict__ cq,
                                             const float* __restrict__ qq,
                                             const float* __restrict__ bias,
                                             float* __restrict__ out) {
  __shared__ __align__(16) char SMEM[64 * 264 * 2];  // PTs, then 2x16KB B-stage
  short* PTs = (short*)SMEM;
  char* Bst = SMEM;
  const int flat = blockIdx.x;                 // 1024 = 8*128 exactly
  const int swz = (flat & 7) * 128 + (flat >> 3);
  const int b = swz >> 5, it = (swz & 31) * 64;
  const int tid = threadIdx.x;
  const int wi = tid >> 6, l = tid & 63, lm = l & 15, lk = l >> 4;

  // ---- phase 1: S via MFMA -> exp -> LDS (raw p), rowsum in-register ----
  float invr[4];
  {
    // fragment-major aS: tileI = it/16 + wi
    bf16x8 aS[4];
    const short* Cf = Cfr + ((size_t)b * 128 + (it >> 4) + wi) * 2048 + (size_t)l * 8;
#pragma unroll
    for (int kk = 0; kk < 4; ++kk) aS[kk] = *(const bf16x8*)(Cf + kk * 512);
    const float bv = bias[0];
    float cqb[4];
#pragma unroll
    for (int r = 0; r < 4; ++r) cqb[r] = cq[b * NLC + it + wi * 16 + lk * 4 + r] + bv;
    const short* Qt0 = Qfr + (size_t)b * 16 * 2048 + (size_t)l * 8;

    float rsum[4] = {0.f, 0.f, 0.f, 0.f};
#pragma unroll
    for (int js = 0; js < 16; ++js) {
      const short* Qjs = Qt0 + (size_t)js * 2048;
      f32x4 c = {0.f, 0.f, 0.f, 0.f};
#pragma unroll
      for (int kk = 0; kk < 4; ++kk)
        c = MFMA16(aS[kk], *(const bf16x8*)(Qjs + kk * 512), c);
      const int j = js * 16 + lm;
      const float qv = qq[b * NLQ + j];
      const int qm = Qmask[b * NLQ + j];
#pragma unroll
      for (int r = 0; r < 4; ++r) {
        float s = c[r] + cqb[r] + qv;
        float v = qm ? s : s + FNEG;
        float p = __expf(v - ESHIFT);
        rsum[r] += p;
        PTs[(wi * 16 + lk * 4 + r) * 264 + js * 16 + lm] = f2bf(p);
      }
    }
#pragma unroll
    for (int off = 1; off < 16; off <<= 1)
#pragma unroll
      for (int r = 0; r < 4; ++r) rsum[r] += __shfl_xor(rsum[r], off, 64);
#pragma unroll
    for (int r = 0; r < 4; ++r) invr[r] = 1.0f / rsum[r];
  }
  __syncthreads();

  // ---- afr (raw p rows) from PTs ----
  bf16x8 afr[8];
#pragma unroll
  for (int kk = 0; kk < 8; ++kk)
    afr[kk] = *(const bf16x8*)&PTs[(wi * 16 + lm) * 264 + kk * 32 + lk * 8];
  __syncthreads();  // all PTs reads done before B-staging overwrite

  // ---- phase 2: double-buffered B-panel staging + MFMA + direct stores ----
  const short* Qp = Qbf + (size_t)b * ND * NLQ;
  const short* Mp = MTbf + (size_t)b * ND * NLQ;
  const short* Cb = Cbf + (size_t)b * ND * NLC;
  float* ob = out + (size_t)b * 4 * ND * NLC;
  const int iB = it + wi * 16 + lk * 4;

  // staging thread mapping: 16 rows x 16 cols of 32B (per panel, 8KB)
  const int srow = tid >> 4, scol = tid & 15;
  const int wsw0 = (((scol * 2) ^ (srow & 7)) << 4);
  const int wsw1 = (((scol * 2 + 1) ^ (srow & 7)) << 4);
  const short* qsrc = Qp + (size_t)srow * NLQ + scol * 16;
  const short* msrc = Mp + (size_t)srow * NLQ + scol * 16;
  bf16x8 sq0, sq1, sm0, sm1;

#define LOADN(n0) { \
    const short* q_ = qsrc + (size_t)(n0) * 16 * NLQ; \
    const short* m_ = msrc + (size_t)(n0) * 16 * NLQ; \
    sq0 = *(const bf16x8*)q_;  sq1 = *(const bf16x8*)(q_ + 8); \
    sm0 = *(const bf16x8*)m_;  sm1 = *(const bf16x8*)(m_ + 8); }
#define WRITEN(buf) { \
    char* base_ = Bst + (buf) * 16384 + srow * 512; \
    *(bf16x8*)(base_ + wsw0) = sq0; *(bf16x8*)(base_ + wsw1) = sq1; \
    *(bf16x8*)(base_ + 8192 + wsw0) = sm0; *(bf16x8*)(base_ + 8192 + wsw1) = sm1; }

  LOADN(0); WRITEN(0);
  __syncthreads();
#pragma unroll
  for (int n0 = 0; n0 < 8; ++n0) {
    if (n0 < 7) LOADN(n0 + 1);                 // issue next-tile loads early
    const int d = n0 * 16 + lm;
    short4 cts = *(const short4*)&Cb[(size_t)d * NLC + iB];  // bf16 ct, early
    const char* bq = Bst + (n0 & 1) * 16384 + lm * 512;
    f32x4 cA = {0.f, 0.f, 0.f, 0.f};
    f32x4 cB = {0.f, 0.f, 0.f, 0.f};
#pragma unroll
    for (int kk = 0; kk < 8; ++kk) {
      const int so = (((kk * 4 + lk) ^ (lm & 7)) << 4);
      cA = MFMA16(afr[kk], *(const bf16x8*)(bq + so), cA);
      cB = MFMA16(afr[kk], *(const bf16x8*)(bq + 8192 + so), cB);
    }
    if (n0 < 7) {
      WRITEN((n0 + 1) & 1);                    // write-late into other buffer
      __syncthreads();
    }
    float4 ct;
    ct.x = bf2f(cts.x); ct.y = bf2f(cts.y); ct.z = bf2f(cts.z); ct.w = bf2f(cts.w);
    float4 av, ca, cb;
    av.x = cA[0] * invr[0]; av.y = cA[1] * invr[1];
    av.z = cA[2] * invr[2]; av.w = cA[3] * invr[3];
    ca.x = ct.x * av.x; ca.y = ct.y * av.y; ca.z = ct.z * av.z; ca.w = ct.w * av.w;
    cb.x = ct.x * cB[0] * invr[0]; cb.y = ct.y * cB[1] * invr[1];
    cb.z = ct.z * cB[2] * invr[2]; cb.w = ct.w * cB[3] * invr[3];
    float* o0 = ob + (size_t)d * NLC + iB;
    *(float4*)o0 = ct;
    *(float4*)(o0 + (size_t)128 * NLC) = av;
    *(float4*)(o0 + (size_t)256 * NLC) = ca;
    *(float4*)(o0 + (size_t)384 * NLC) = cb;
  }
#undef LOADN
#undef WRITEN
}

// ---------------------------------------------------------------------------
extern "C" void kernel_launch(void* const* d_in, const int* in_sizes, int n_in,
                              void* d_out, int out_size, void* d_ws, size_t ws_size,
                              hipStream_t stream) {
  const float* C = (const float*)d_in[0];
  const float* Q = (const float*)d_in[1];
  const int* Cmask = (const int*)d_in[2];
  const int* Qmask = (const int*)d_in[3];
  const float* w4C = (const float*)d_in[4];
  const float* w4Q = (const float*)d_in[5];
  const float* w4mlu = (const float*)d_in[6];
  const float* bias = (const float*)d_in[7];
  float* out = (float*)d_out;

  short* Cfr = (short*)d_ws;                           // [b][128 tiles][4][64][8]
  short* Cbf = Cfr + (size_t)NB * NLC * ND;            // [b][D][Lc]
  short* Qfr = Cbf + (size_t)NB * NLC * ND;            // [b][16 tiles][4][64][8] (w4mlu folded)
  short* Qbf = Qfr + (size_t)NB * NLQ * ND;            // [b][D][Lq]
  short* MTbf = Qbf + (size_t)NB * NLQ * ND;           // [b][D][Lq]
  float* cq = (float*)(MTbf + (size_t)NB * ND * NLQ);
  float* qq = cq + NB * NLC;
  size_t need = (size_t)(qq + NB * NLQ - (float*)d_ws) * sizeof(float);
  if (ws_size < need) return;  // fail loudly rather than corrupt

  hipMemsetAsync(cq, 0, (size_t)(NB * NLC + NB * NLQ) * sizeof(float), stream);
  k_tr<<<dim3(NLC / 64, ND / 32, NB), 256, 0, stream>>>(C, nullptr, w4C, Cfr, Cbf, cq, NLC);
  k_tr<<<dim3(NLQ / 64, ND / 32, NB), 256, 0, stream>>>(Q, w4mlu, w4Q, Qfr, Qbf, qq, NLQ);
  k_MT<<<256, 512, 0, stream>>>(Cfr, Qfr, Cbf, Cmask, cq, qq, bias, MTbf);
  k_PAB<<<1024, 256, 0, stream>>>(Cbf, Cfr, Qfr, Qbf, MTbf, Qmask, cq, qq, bias, out);
}

// Round 16
// 108.750 us; speedup vs baseline: 1.3804x; 1.0634x over previous
//
#include <hip/hip_runtime.h>
#include <cstdint>

// CQAttention: B=32, D=128, Lc=2048, Lq=256, f32 in/out.
// Pipeline (R16):
//   memset  : zero cq/qq accumulators (260KB)
//   k_tr x2 : bf16 copies + fused dot products. Transposed outputs are
//             FRAGMENT-MAJOR (R15): [b][tile=j>>4][kk=d>>5][lane][8].
//             R16: C's natural copy replaced by Cafr, fragment-major for
//             the MT-GEMM A-side: [b][dtile=d>>4][ichunk=i>>5][lane=
//             ((i>>3)&3)*16+(d&15)][pos=i&7] (amode=1). Q keeps natural
//             [b][d][q] (amode=0) for k_PAB's B-panel staging.
//   k_MT    : QT=32, XCD swizzle (R14), fragment-major aq/Ct loads (R15),
//             R16: A-loads from Cafr = one contiguous 1KB per wave instr
//             (was 16 scattered 64B segments at stride 4KB).
//   k_PAB   : fused row-softmax + A/Bt GEMMs, double-buffered LDS B-panel
//             staging (R12), fragment-major phase-1 loads (R15), ct stream
//             re-indexed into Cafr (R16).
// Bt = S1 @ (S2^T @ Ct) associativity rewrite avoids the Lc x Lc matrix.

#define NB 32
#define ND 128
#define NLC 2048
#define NLQ 256
#define FNEG (-1.0e30f)
#define ESHIFT 20.0f

typedef __attribute__((ext_vector_type(8))) short bf16x8;
typedef __attribute__((ext_vector_type(4))) float f32x4;
#define MFMA16(a, b, c) __builtin_amdgcn_mfma_f32_16x16x32_bf16(a, b, c, 0, 0, 0)

__device__ __forceinline__ short f2bf(float x) {
  union { float f; unsigned u; } v; v.f = x;
  unsigned r = (v.u + 0x7FFFu + ((v.u >> 16) & 1u)) >> 16;
  return (short)r;
}
__device__ __forceinline__ float bf2f(short x) {
  union { unsigned u; float f; } v; v.u = ((unsigned)(unsigned short)x) << 16;
  return v.f;
}

// ------- bf16 copies (fragment-major transposed + amode copy) + fused dot --
// in [b][ND][L] f32 ->
//   outT fragment-major: [b][L/16 tiles][4 kk][64 lanes][8 bf16] (x wvec[d])
//   outN: amode=0 natural [b][ND][L]; amode=1 MT-A fragment-major
//         [b][dtile][ichunk][lane][8]
//   dotv[b*L+i] += sum_dd in[b,d0+dd,i]*wdot[d0+dd]
__global__ __launch_bounds__(256) void k_tr(const float* __restrict__ in,
                                            const float* __restrict__ wvec,
                                            const float* __restrict__ wdot,
                                            short* __restrict__ outT,
                                            short* __restrict__ outN,
                                            float* __restrict__ dotv, int L,
                                            int amode) {
  __shared__ float T[32][66];
  const int b = blockIdx.z, d0 = blockIdx.y * 32, i0 = blockIdx.x * 64;
  const int t = threadIdx.x;
#pragma unroll
  for (int rr = 0; rr < 2; ++rr) {
    int idx = t + rr * 256;
    int dd = idx >> 4, c4 = idx & 15;
    const float* src = in + ((size_t)b * ND + d0 + dd) * L + i0 + c4 * 4;
    float4 v = *(const float4*)src;
    T[dd][c4 * 4 + 0] = v.x;
    T[dd][c4 * 4 + 1] = v.y;
    T[dd][c4 * 4 + 2] = v.z;
    T[dd][c4 * 4 + 3] = v.w;
    if (outN && amode == 0) {
      short4 o;
      o.x = f2bf(v.x); o.y = f2bf(v.y); o.z = f2bf(v.z); o.w = f2bf(v.w);
      *(short4*)(outN + ((size_t)b * ND + d0 + dd) * L + i0 + c4 * 4) = o;
    }
  }
  __syncthreads();
  // fused dot: threads 0-63 accumulate this d0-block's partial into dotv
  if (t < 64) {
    float s = 0.f;
#pragma unroll
    for (int dd = 0; dd < 32; ++dd) s = fmaf(T[dd][t], wdot[d0 + dd], s);
    atomicAdd(&dotv[(size_t)b * L + i0 + t], s);
  }
  // MT-A fragment-major store (amode=1): thread -> (dt_loc, ic_loc, lane)
  if (outN && amode == 1) {
    const int dt_loc = t & 1, ic_loc = (t >> 1) & 1, lane = t >> 2;
    const int dd = dt_loc * 16 + (lane & 15);
    const int ibase = ic_loc * 32 + ((lane >> 4) & 3) * 8;
    bf16x8 pk;
#pragma unroll
    for (int k = 0; k < 8; ++k) pk[k] = f2bf(T[dd][ibase + k]);
    const size_t dtile = (size_t)((d0 >> 4) + dt_loc);
    const size_t ichunk = (size_t)((i0 >> 5) + ic_loc);
    *(bf16x8*)(outN + (((size_t)b * 8 + dtile) * (size_t)(L >> 5) + ichunk) * 512 +
               (size_t)lane * 8) = pk;
  }
  const int i = t >> 2, seg = t & 3;
  bf16x8 pack;
#pragma unroll
  for (int k = 0; k < 8; ++k) {
    int d = seg * 8 + k;
    float x = T[d][i];
    if (wvec) x *= wvec[d0 + d];
    pack[k] = f2bf(x);
  }
  // fragment-major store: tile=(i0+i)>>4, kk=d0>>5, lane=seg*16+((i0+i)&15)
  {
    const size_t tile = (size_t)((i0 + i) >> 4);
    const int lane = seg * 16 + ((i0 + i) & 15);
    *(bf16x8*)(outT + ((size_t)b * (L >> 4) + tile) * 2048 +
               (size_t)(d0 >> 5) * 512 + (size_t)lane * 8) = pack;
  }
}

// ---------------- k_MT: MT[b,d,q] = sum_i softmax_col(S)[i,q] * C[b,d,i] ---
// 1D grid 256 blocks (8 XCD x 32: XCD k -> batches 4k..4k+3), 512 thr.
// QT=32. Fragment-major aq/Ct loads (R15) + Cafr A-loads (R16).
__global__ __launch_bounds__(512) void k_MT(const short* __restrict__ Cfr,
                                            const short* __restrict__ Qfr,
                                            const short* __restrict__ Cafr,
                                            const int* __restrict__ Cmask,
                                            const float* __restrict__ cq,
                                            const float* __restrict__ qq,
                                            const float* __restrict__ bias,
                                            short* __restrict__ MTbf) {
  __shared__ short PTs[32 * 136];   // P2^T bf16 [q 32][i-chunk 128], pad->136
  __shared__ float cspart[8][32];
  __shared__ float bc[32];
  const int flat = blockIdx.x;                 // 256 = 8*32 exactly
  const int swz = (flat & 7) * 32 + (flat >> 3);
  const int b = swz >> 3, qt = (swz & 7) * 32;
  const int tid = threadIdx.x;
  const int w = tid >> 6, l = tid & 63, lm = l & 15, lk = l >> 4;
  const int qsub = w & 1, ipair = w >> 1;
  const float bv = bias[0];

  // fragment-major aq: tileJ = qt/16 + qsub
  bf16x8 aq[4];
  {
    const short* Qf = Qfr + ((size_t)b * 16 + (qt >> 4) + qsub) * 2048 + (size_t)l * 8;
#pragma unroll
    for (int kk = 0; kk < 4; ++kk) aq[kk] = *(const bf16x8*)(Qf + kk * 512);
  }
  float qqv[4];
#pragma unroll
  for (int r = 0; r < 4; ++r) qqv[r] = qq[b * NLQ + qt + qsub * 16 + lk * 4 + r];

  float csacc[4] = {0.f, 0.f, 0.f, 0.f};
  f32x4 accMT[2] = {{0.f, 0.f, 0.f, 0.f}, {0.f, 0.f, 0.f, 0.f}};
  for (int i0 = 0; i0 < NLC; i0 += 128) {
#pragma unroll
    for (int t2 = 0; t2 < 2; ++t2) {
      const int isub = ipair * 2 + t2;
      const int iCol = i0 + isub * 16 + lm;
      // fragment-major Ct tile: tileI = i0/16 + isub
      const short* Cf = Cfr + ((size_t)b * 128 + (i0 >> 4) + isub) * 2048 + (size_t)l * 8;
      f32x4 c = {0.f, 0.f, 0.f, 0.f};
#pragma unroll
      for (int kk = 0; kk < 4; ++kk)
        c = MFMA16(aq[kk], *(const bf16x8*)(Cf + kk * 512), c);
      const float cqb = cq[b * NLC + iCol] + bv;
      const int cm = Cmask[b * NLC + iCol];
#pragma unroll
      for (int r = 0; r < 4; ++r) {
        float s = c[r] + cqb + qqv[r];
        float v = cm ? s : s + FNEG;
        float p = __expf(v - ESHIFT);
        csacc[r] += p;
        PTs[(qsub * 16 + lk * 4 + r) * 136 + isub * 16 + lm] = f2bf(p);
      }
    }
    __syncthreads();
    // MT GEMM: A[m=d]=Cafr fragment-major (1KB/wave-instr), B=P^T from LDS
    const short* Arow = Cafr + (((size_t)b * 8 + w) * 64 + (i0 >> 5)) * 512 + (size_t)l * 8;
#pragma unroll
    for (int ks = 0; ks < 4; ++ks) {
      bf16x8 a = *(const bf16x8*)(Arow + ks * 512);
#pragma unroll
      for (int qs = 0; qs < 2; ++qs) {
        bf16x8 bb = *(const bf16x8*)&PTs[(qs * 16 + lm) * 136 + ks * 32 + lk * 8];
        accMT[qs] = MFMA16(a, bb, accMT[qs]);
      }
    }
    __syncthreads();
  }
  // colsum reduce
#pragma unroll
  for (int off = 1; off < 16; off <<= 1)
#pragma unroll
    for (int r = 0; r < 4; ++r) csacc[r] += __shfl_xor(csacc[r], off, 64);
  if (lm == 0) {
#pragma unroll
    for (int r = 0; r < 4; ++r) cspart[w][qsub * 16 + lk * 4 + r] = csacc[r];
  }
  __syncthreads();
  if (tid < 32) {
    const int base = (tid >> 4) & 1;
    float s = 0.f;
#pragma unroll
    for (int k2 = 0; k2 < 4; ++k2) s += cspart[k2 * 2 + base][tid];
    bc[tid] = 1.0f / s;
  }
  __syncthreads();
#pragma unroll
  for (int qs = 0; qs < 2; ++qs) {
    const float inv = bc[qs * 16 + lm];
#pragma unroll
    for (int r = 0; r < 4; ++r)
      MTbf[((size_t)b * ND + w * 16 + lk * 4 + r) * NLQ + qt + qs * 16 + lm] =
          f2bf(accMT[qs][r] * inv);
  }
}

// ---------------- k_PAB: fused softmax + A/Bt GEMMs, LDS B-staging ---------
// 1D grid 1024 blocks (XCD-bijective swizzle). 256 thr (4 waves).
// Phase 1: fragment-major aS/Q loads (R15). Phase 2: double-buffered LDS
// B-panel staging (R12); ct stream from Cafr (R16).
__global__ __launch_bounds__(256) void k_PAB(const short* __restrict__ Cafr,
                                             const short* __restrict__ Cfr,
                                             const short* __restrict__ Qfr,
                                             const short* __restrict__ Qbf,
                                             const short* __restrict__ MTbf,
                                             const int* __restrict__ Qmask,
                                             const float* __restrict__ cq,
                                             const float* __restrict__ qq,
                                             const float* __restrict__ bias,
                                             float* __restrict__ out) {
  __shared__ __align__(16) char SMEM[64 * 264 * 2];  // PTs, then 2x16KB B-stage
  short* PTs = (short*)SMEM;
  char* Bst = SMEM;
  const int flat = blockIdx.x;                 // 1024 = 8*128 exactly
  const int swz = (flat & 7) * 128 + (flat >> 3);
  const int b = swz >> 5, it = (swz & 31) * 64;
  const int tid = threadIdx.x;
  const int wi = tid >> 6, l = tid & 63, lm = l & 15, lk = l >> 4;

  // ---- phase 1: S via MFMA -> exp -> LDS (raw p), rowsum in-register ----
  float invr[4];
  {
    // fragment-major aS: tileI = it/16 + wi
    bf16x8 aS[4];
    const short* Cf = Cfr + ((size_t)b * 128 + (it >> 4) + wi) * 2048 + (size_t)l * 8;
#pragma unroll
    for (int kk = 0; kk < 4; ++kk) aS[kk] = *(const bf16x8*)(Cf + kk * 512);
    const float bv = bias[0];
    float cqb[4];
#pragma unroll
    for (int r = 0; r < 4; ++r) cqb[r] = cq[b * NLC + it + wi * 16 + lk * 4 + r] + bv;
    const short* Qt0 = Qfr + (size_t)b * 16 * 2048 + (size_t)l * 8;

    float rsum[4] = {0.f, 0.f, 0.f, 0.f};
#pragma unroll
    for (int js = 0; js < 16; ++js) {
      const short* Qjs = Qt0 + (size_t)js * 2048;
      f32x4 c = {0.f, 0.f, 0.f, 0.f};
#pragma unroll
      for (int kk = 0; kk < 4; ++kk)
        c = MFMA16(aS[kk], *(const bf16x8*)(Qjs + kk * 512), c);
      const int j = js * 16 + lm;
      const float qv = qq[b * NLQ + j];
      const int qm = Qmask[b * NLQ + j];
#pragma unroll
      for (int r = 0; r < 4; ++r) {
        float s = c[r] + cqb[r] + qv;
        float v = qm ? s : s + FNEG;
        float p = __expf(v - ESHIFT);
        rsum[r] += p;
        PTs[(wi * 16 + lk * 4 + r) * 264 + js * 16 + lm] = f2bf(p);
      }
    }
#pragma unroll
    for (int off = 1; off < 16; off <<= 1)
#pragma unroll
      for (int r = 0; r < 4; ++r) rsum[r] += __shfl_xor(rsum[r], off, 64);
#pragma unroll
    for (int r = 0; r < 4; ++r) invr[r] = 1.0f / rsum[r];
  }
  __syncthreads();

  // ---- afr (raw p rows) from PTs ----
  bf16x8 afr[8];
#pragma unroll
  for (int kk = 0; kk < 8; ++kk)
    afr[kk] = *(const bf16x8*)&PTs[(wi * 16 + lm) * 264 + kk * 32 + lk * 8];
  __syncthreads();  // all PTs reads done before B-staging overwrite

  // ---- phase 2: double-buffered B-panel staging + MFMA + direct stores ----
  const short* Qp = Qbf + (size_t)b * ND * NLQ;
  const short* Mp = MTbf + (size_t)b * ND * NLQ;
  float* ob = out + (size_t)b * 4 * ND * NLC;
  const int iB = it + wi * 16 + lk * 4;
  // ct from Cafr: n0-invariant part of the offset
  const size_t cbase = ((size_t)b * 8 * 64 + (size_t)(iB >> 5)) * 512 +
                       (size_t)(((iB >> 3) & 3) * 16 + lm) * 8 + (size_t)(iB & 7);

  // staging thread mapping: 16 rows x 16 cols of 32B (per panel, 8KB)
  const int srow = tid >> 4, scol = tid & 15;
  const int wsw0 = (((scol * 2) ^ (srow & 7)) << 4);
  const int wsw1 = (((scol * 2 + 1) ^ (srow & 7)) << 4);
  const short* qsrc = Qp + (size_t)srow * NLQ + scol * 16;
  const short* msrc = Mp + (size_t)srow * NLQ + scol * 16;
  bf16x8 sq0, sq1, sm0, sm1;

#define LOADN(n0) { \
    const short* q_ = qsrc + (size_t)(n0) * 16 * NLQ; \
    const short* m_ = msrc + (size_t)(n0) * 16 * NLQ; \
    sq0 = *(const bf16x8*)q_;  sq1 = *(const bf16x8*)(q_ + 8); \
    sm0 = *(const bf16x8*)m_;  sm1 = *(const bf16x8*)(m_ + 8); }
#define WRITEN(buf) { \
    char* base_ = Bst + (buf) * 16384 + srow * 512; \
    *(bf16x8*)(base_ + wsw0) = sq0; *(bf16x8*)(base_ + wsw1) = sq1; \
    *(bf16x8*)(base_ + 8192 + wsw0) = sm0; *(bf16x8*)(base_ + 8192 + wsw1) = sm1; }

  LOADN(0); WRITEN(0);
  __syncthreads();
#pragma unroll
  for (int n0 = 0; n0 < 8; ++n0) {
    if (n0 < 7) LOADN(n0 + 1);                 // issue next-tile loads early
    const int d = n0 * 16 + lm;
    short4 cts = *(const short4*)&Cafr[cbase + (size_t)n0 * 64 * 512];  // bf16 ct
    const char* bq = Bst + (n0 & 1) * 16384 + lm * 512;
    f32x4 cA = {0.f, 0.f, 0.f, 0.f};
    f32x4 cB = {0.f, 0.f, 0.f, 0.f};
#pragma unroll
    for (int kk = 0; kk < 8; ++kk) {
      const int so = (((kk * 4 + lk) ^ (lm & 7)) << 4);
      cA = MFMA16(afr[kk], *(const bf16x8*)(bq + so), cA);
      cB = MFMA16(afr[kk], *(const bf16x8*)(bq + 8192 + so), cB);
    }
    if (n0 < 7) {
      WRITEN((n0 + 1) & 1);                    // write-late into other buffer
      __syncthreads();
    }
    float4 ct;
    ct.x = bf2f(cts.x); ct.y = bf2f(cts.y); ct.z = bf2f(cts.z); ct.w = bf2f(cts.w);
    float4 av, ca, cb;
    av.x = cA[0] * invr[0]; av.y = cA[1] * invr[1];
    av.z = cA[2] * invr[2]; av.w = cA[3] * invr[3];
    ca.x = ct.x * av.x; ca.y = ct.y * av.y; ca.z = ct.z * av.z; ca.w = ct.w * av.w;
    cb.x = ct.x * cB[0] * invr[0]; cb.y = ct.y * cB[1] * invr[1];
    cb.z = ct.z * cB[2] * invr[2]; cb.w = ct.w * cB[3] * invr[3];
    float* o0 = ob + (size_t)d * NLC + iB;
    *(float4*)o0 = ct;
    *(float4*)(o0 + (size_t)128 * NLC) = av;
    *(float4*)(o0 + (size_t)256 * NLC) = ca;
    *(float4*)(o0 + (size_t)384 * NLC) = cb;
  }
#undef LOADN
#undef WRITEN
}

// ---------------------------------------------------------------------------
extern "C" void kernel_launch(void* const* d_in, const int* in_sizes, int n_in,
                              void* d_out, int out_size, void* d_ws, size_t ws_size,
                              hipStream_t stream) {
  const float* C = (const float*)d_in[0];
  const float* Q = (const float*)d_in[1];
  const int* Cmask = (const int*)d_in[2];
  const int* Qmask = (const int*)d_in[3];
  const float* w4C = (const float*)d_in[4];
  const float* w4Q = (const float*)d_in[5];
  const float* w4mlu = (const float*)d_in[6];
  const float* bias = (const float*)d_in[7];
  float* out = (float*)d_out;

  short* Cfr = (short*)d_ws;                           // [b][128 tiles][4][64][8]
  short* Cafr = Cfr + (size_t)NB * NLC * ND;           // [b][8 dt][64 ic][64][8]
  short* Qfr = Cafr + (size_t)NB * NLC * ND;           // [b][16 tiles][4][64][8] (w4mlu folded)
  short* Qbf = Qfr + (size_t)NB * NLQ * ND;            // [b][D][Lq]
  short* MTbf = Qbf + (size_t)NB * NLQ * ND;           // [b][D][Lq]
  float* cq = (float*)(MTbf + (size_t)NB * ND * NLQ);
  float* qq = cq + NB * NLC;
  size_t need = (size_t)(qq + NB * NLQ - (float*)d_ws) * sizeof(float);
  if (ws_size < need) return;  // fail loudly rather than corrupt

  hipMemsetAsync(cq, 0, (size_t)(NB * NLC + NB * NLQ) * sizeof(float), stream);
  k_tr<<<dim3(NLC / 64, ND / 32, NB), 256, 0, stream>>>(C, nullptr, w4C, Cfr, Cafr, cq, NLC, 1);
  k_tr<<<dim3(NLQ / 64, ND / 32, NB), 256, 0, stream>>>(Q, w4mlu, w4Q, Qfr, Qbf, qq, NLQ, 0);
  k_MT<<<256, 512, 0, stream>>>(Cfr, Qfr, Cafr, Cmask, cq, qq, bias, MTbf);
  k_PAB<<<1024, 256, 0, stream>>>(Cafr, Cfr, Qfr, Qbf, MTbf, Qmask, cq, qq, bias, out);
}

// Round 17
// 93.885 us; speedup vs baseline: 1.5990x; 1.1583x over previous
//
#include <hip/hip_runtime.h>
#include <cstdint>

// CQAttention: B=32, D=128, Lc=2048, Lq=256, f32 in/out.
// Pipeline (R17):
//   memset  : zero cq/qq accumulators (260KB)
//   k_tr x2 : bf16 copies + fused dot products. Cfr/Qfr fragment-major
//             (R15); Cafr MT-A fragment-major (R16); R17: k_tr(Q) also
//             builds mskE[b][j] = Qmask ? 0xFFFF : 0 (bf16 AND-mask).
//   k_MT    : QT=32, XCD swizzle, fragment-major loads. R17: stores the
//             UNMASKED pu = exp(s-20) to E fragment-major [b][itile][kk]
//             [lane][8] (the exact afr layout k_PAB consumes) while using
//             the Cmask-masked copy for its own PTs/colsum. S is now
//             computed exactly once in the whole pipeline.
//   k_PAB   : R17: phase 1 (S recompute + exp + PTs round-trip) DELETED.
//             afr loads straight from E (8x1KB contiguous), Qmask applied
//             via bitwise AND with mskE, rowsum = in-register bf16 sum +
//             shfl reduce. Phase 2 unchanged (R12 B-panel staging, R16
//             Cafr ct stream).
// Bt = S1 @ (S2^T @ Ct) associativity rewrite avoids the Lc x Lc matrix.

#define NB 32
#define ND 128
#define NLC 2048
#define NLQ 256
#define FNEG (-1.0e30f)
#define ESHIFT 20.0f

typedef __attribute__((ext_vector_type(8))) short bf16x8;
typedef __attribute__((ext_vector_type(4))) float f32x4;
#define MFMA16(a, b, c) __builtin_amdgcn_mfma_f32_16x16x32_bf16(a, b, c, 0, 0, 0)

__device__ __forceinline__ short f2bf(float x) {
  union { float f; unsigned u; } v; v.f = x;
  unsigned r = (v.u + 0x7FFFu + ((v.u >> 16) & 1u)) >> 16;
  return (short)r;
}
__device__ __forceinline__ float bf2f(short x) {
  union { unsigned u; float f; } v; v.u = ((unsigned)(unsigned short)x) << 16;
  return v.f;
}

// ------- bf16 copies (fragment-major) + fused dot + (Q) mskE build --------
__global__ __launch_bounds__(256) void k_tr(const float* __restrict__ in,
                                            const float* __restrict__ wvec,
                                            const float* __restrict__ wdot,
                                            short* __restrict__ outT,
                                            short* __restrict__ outN,
                                            float* __restrict__ dotv, int L,
                                            int amode,
                                            const int* __restrict__ qmask,
                                            short* __restrict__ mskE) {
  __shared__ float T[32][66];
  const int b = blockIdx.z, d0 = blockIdx.y * 32, i0 = blockIdx.x * 64;
  const int t = threadIdx.x;
#pragma unroll
  for (int rr = 0; rr < 2; ++rr) {
    int idx = t + rr * 256;
    int dd = idx >> 4, c4 = idx & 15;
    const float* src = in + ((size_t)b * ND + d0 + dd) * L + i0 + c4 * 4;
    float4 v = *(const float4*)src;
    T[dd][c4 * 4 + 0] = v.x;
    T[dd][c4 * 4 + 1] = v.y;
    T[dd][c4 * 4 + 2] = v.z;
    T[dd][c4 * 4 + 3] = v.w;
    if (outN && amode == 0) {
      short4 o;
      o.x = f2bf(v.x); o.y = f2bf(v.y); o.z = f2bf(v.z); o.w = f2bf(v.w);
      *(short4*)(outN + ((size_t)b * ND + d0 + dd) * L + i0 + c4 * 4) = o;
    }
  }
  __syncthreads();
  // fused dot: threads 0-63 accumulate this d0-block's partial into dotv
  if (t < 64) {
    float s = 0.f;
#pragma unroll
    for (int dd = 0; dd < 32; ++dd) s = fmaf(T[dd][t], wdot[d0 + dd], s);
    atomicAdd(&dotv[(size_t)b * L + i0 + t], s);
  }
  // mskE build (Q path, one d0-block only)
  if (mskE && blockIdx.y == 0 && t < 64) {
    const int j = i0 + t;
    mskE[(size_t)b * NLQ + j] = qmask[b * NLQ + j] ? (short)0xFFFF : (short)0;
  }
  // MT-A fragment-major store (amode=1)
  if (outN && amode == 1) {
    const int dt_loc = t & 1, ic_loc = (t >> 1) & 1, lane = t >> 2;
    const int dd = dt_loc * 16 + (lane & 15);
    const int ibase = ic_loc * 32 + ((lane >> 4) & 3) * 8;
    bf16x8 pk;
#pragma unroll
    for (int k = 0; k < 8; ++k) pk[k] = f2bf(T[dd][ibase + k]);
    const size_t dtile = (size_t)((d0 >> 4) + dt_loc);
    const size_t ichunk = (size_t)((i0 >> 5) + ic_loc);
    *(bf16x8*)(outN + (((size_t)b * 8 + dtile) * (size_t)(L >> 5) + ichunk) * 512 +
               (size_t)lane * 8) = pk;
  }
  const int i = t >> 2, seg = t & 3;
  bf16x8 pack;
#pragma unroll
  for (int k = 0; k < 8; ++k) {
    int d = seg * 8 + k;
    float x = T[d][i];
    if (wvec) x *= wvec[d0 + d];
    pack[k] = f2bf(x);
  }
  {
    const size_t tile = (size_t)((i0 + i) >> 4);
    const int lane = seg * 16 + ((i0 + i) & 15);
    *(bf16x8*)(outT + ((size_t)b * (L >> 4) + tile) * 2048 +
               (size_t)(d0 >> 5) * 512 + (size_t)lane * 8) = pack;
  }
}

// ---------------- k_MT: MT GEMM + E materialization ------------------------
// 1D grid 256 blocks (8 XCD x 32), 512 thr. QT=32. R17: also writes the
// unmasked pu=exp(s-20) to E fragment-major (k_PAB's afr layout).
__global__ __launch_bounds__(512) void k_MT(const short* __restrict__ Cfr,
                                            const short* __restrict__ Qfr,
                                            const short* __restrict__ Cafr,
                                            const int* __restrict__ Cmask,
                                            const float* __restrict__ cq,
                                            const float* __restrict__ qq,
                                            const float* __restrict__ bias,
                                            short* __restrict__ MTbf,
                                            short* __restrict__ E) {
  __shared__ short PTs[32 * 136];   // P2^T bf16 [q 32][i-chunk 128], pad->136
  __shared__ float cspart[8][32];
  __shared__ float bc[32];
  const int flat = blockIdx.x;                 // 256 = 8*32 exactly
  const int swz = (flat & 7) * 32 + (flat >> 3);
  const int b = swz >> 3, qt = (swz & 7) * 32;
  const int tid = threadIdx.x;
  const int w = tid >> 6, l = tid & 63, lm = l & 15, lk = l >> 4;
  const int qsub = w & 1, ipair = w >> 1;
  const float bv = bias[0];

  bf16x8 aq[4];
  {
    const short* Qf = Qfr + ((size_t)b * 16 + (qt >> 4) + qsub) * 2048 + (size_t)l * 8;
#pragma unroll
    for (int kk = 0; kk < 4; ++kk) aq[kk] = *(const bf16x8*)(Qf + kk * 512);
  }
  float qqv[4];
#pragma unroll
  for (int r = 0; r < 4; ++r) qqv[r] = qq[b * NLQ + qt + qsub * 16 + lk * 4 + r];

  // E store base for this thread (itile/kk parts added in loop)
  const int elane = (qsub * 2 + (lk >> 1)) * 16 + lm;
  short* Eb = E + (size_t)b * 128 * 4096 + (size_t)(qt >> 5) * 512 +
              (size_t)elane * 8 + (lk & 1) * 4;

  float csacc[4] = {0.f, 0.f, 0.f, 0.f};
  f32x4 accMT[2] = {{0.f, 0.f, 0.f, 0.f}, {0.f, 0.f, 0.f, 0.f}};
  for (int i0 = 0; i0 < NLC; i0 += 128) {
#pragma unroll
    for (int t2 = 0; t2 < 2; ++t2) {
      const int isub = ipair * 2 + t2;
      const int iCol = i0 + isub * 16 + lm;
      const short* Cf = Cfr + ((size_t)b * 128 + (i0 >> 4) + isub) * 2048 + (size_t)l * 8;
      f32x4 c = {0.f, 0.f, 0.f, 0.f};
#pragma unroll
      for (int kk = 0; kk < 4; ++kk)
        c = MFMA16(aq[kk], *(const bf16x8*)(Cf + kk * 512), c);
      const float cqb = cq[b * NLC + iCol] + bv;
      const int cm = Cmask[b * NLC + iCol];
      short ev[4];
#pragma unroll
      for (int r = 0; r < 4; ++r) {
        float s = c[r] + cqb + qqv[r];
        float pu = __expf(s - ESHIFT);       // unmasked -> E
        float pm = cm ? pu : 0.f;            // Cmask-masked -> PTs/colsum
        csacc[r] += pm;
        PTs[(qsub * 16 + lk * 4 + r) * 136 + isub * 16 + lm] = f2bf(pm);
        ev[r] = f2bf(pu);
      }
      *(short4*)(Eb + (size_t)((i0 >> 4) + isub) * 4096) = *(short4*)ev;
    }
    __syncthreads();
    // MT GEMM: A[m=d]=Cafr fragment-major, B=P^T from LDS
    const short* Arow = Cafr + (((size_t)b * 8 + w) * 64 + (i0 >> 5)) * 512 + (size_t)l * 8;
#pragma unroll
    for (int ks = 0; ks < 4; ++ks) {
      bf16x8 a = *(const bf16x8*)(Arow + ks * 512);
#pragma unroll
      for (int qs = 0; qs < 2; ++qs) {
        bf16x8 bb = *(const bf16x8*)&PTs[(qs * 16 + lm) * 136 + ks * 32 + lk * 8];
        accMT[qs] = MFMA16(a, bb, accMT[qs]);
      }
    }
    __syncthreads();
  }
  // colsum reduce
#pragma unroll
  for (int off = 1; off < 16; off <<= 1)
#pragma unroll
    for (int r = 0; r < 4; ++r) csacc[r] += __shfl_xor(csacc[r], off, 64);
  if (lm == 0) {
#pragma unroll
    for (int r = 0; r < 4; ++r) cspart[w][qsub * 16 + lk * 4 + r] = csacc[r];
  }
  __syncthreads();
  if (tid < 32) {
    const int base = (tid >> 4) & 1;
    float s = 0.f;
#pragma unroll
    for (int k2 = 0; k2 < 4; ++k2) s += cspart[k2 * 2 + base][tid];
    bc[tid] = 1.0f / s;
  }
  __syncthreads();
#pragma unroll
  for (int qs = 0; qs < 2; ++qs) {
    const float inv = bc[qs * 16 + lm];
#pragma unroll
    for (int r = 0; r < 4; ++r)
      MTbf[((size_t)b * ND + w * 16 + lk * 4 + r) * NLQ + qt + qs * 16 + lm] =
          f2bf(accMT[qs][r] * inv);
  }
}

// ---------------- k_PAB: A/Bt GEMMs from E, LDS B-staging ------------------
// 1D grid 1024 blocks (XCD-bijective swizzle). 256 thr (4 waves).
// R17: afr loaded straight from E (masked via mskE AND); rowsum in-register.
__global__ __launch_bounds__(256) void k_PAB(const short* __restrict__ Cafr,
                                             const short* __restrict__ E,
                                             const short* __restrict__ mskE,
                                             const short* __restrict__ Qbf,
                                             const short* __restrict__ MTbf,
                                             float* __restrict__ out) {
  __shared__ __align__(16) char Bst[32768];    // 2x16KB B-stage
  const int flat = blockIdx.x;                 // 1024 = 8*128 exactly
  const int swz = (flat & 7) * 128 + (flat >> 3);
  const int b = swz >> 5, it = (swz & 31) * 64;
  const int tid = threadIdx.x;
  const int wi = tid >> 6, l = tid & 63, lm = l & 15, lk = l >> 4;

  // ---- afr from E (Qmask via AND), rowsum via shfl ----
  bf16x8 afr[8];
  {
    const short* Ef = E + ((size_t)b * 128 + (it >> 4) + wi) * 4096 + (size_t)l * 8;
    const short* mb = mskE + (size_t)b * NLQ + lk * 8;
#pragma unroll
    for (int kk = 0; kk < 8; ++kk) {
      bf16x8 a = *(const bf16x8*)(Ef + kk * 512);
      bf16x8 m = *(const bf16x8*)(mb + kk * 32);
      afr[kk] = a & m;
    }
  }
  float rsum = 0.f;
#pragma unroll
  for (int kk = 0; kk < 8; ++kk)
#pragma unroll
    for (int e = 0; e < 8; ++e) rsum += bf2f(afr[kk][e]);
  rsum += __shfl_xor(rsum, 16, 64);
  rsum += __shfl_xor(rsum, 32, 64);
  float invr[4];
#pragma unroll
  for (int r = 0; r < 4; ++r)
    invr[r] = 1.0f / __shfl(rsum, (l & 48) + lk * 4 + r, 64);

  // ---- phase 2: double-buffered B-panel staging + MFMA + direct stores ----
  const short* Qp = Qbf + (size_t)b * ND * NLQ;
  const short* Mp = MTbf + (size_t)b * ND * NLQ;
  float* ob = out + (size_t)b * 4 * ND * NLC;
  const int iB = it + wi * 16 + lk * 4;
  const size_t cbase = ((size_t)b * 8 * 64 + (size_t)(iB >> 5)) * 512 +
                       (size_t)(((iB >> 3) & 3) * 16 + lm) * 8 + (size_t)(iB & 7);

  const int srow = tid >> 4, scol = tid & 15;
  const int wsw0 = (((scol * 2) ^ (srow & 7)) << 4);
  const int wsw1 = (((scol * 2 + 1) ^ (srow & 7)) << 4);
  const short* qsrc = Qp + (size_t)srow * NLQ + scol * 16;
  const short* msrc = Mp + (size_t)srow * NLQ + scol * 16;
  bf16x8 sq0, sq1, sm0, sm1;

#define LOADN(n0) { \
    const short* q_ = qsrc + (size_t)(n0) * 16 * NLQ; \
    const short* m_ = msrc + (size_t)(n0) * 16 * NLQ; \
    sq0 = *(const bf16x8*)q_;  sq1 = *(const bf16x8*)(q_ + 8); \
    sm0 = *(const bf16x8*)m_;  sm1 = *(const bf16x8*)(m_ + 8); }
#define WRITEN(buf) { \
    char* base_ = Bst + (buf) * 16384 + srow * 512; \
    *(bf16x8*)(base_ + wsw0) = sq0; *(bf16x8*)(base_ + wsw1) = sq1; \
    *(bf16x8*)(base_ + 8192 + wsw0) = sm0; *(bf16x8*)(base_ + 8192 + wsw1) = sm1; }

  LOADN(0); WRITEN(0);
  __syncthreads();
#pragma unroll
  for (int n0 = 0; n0 < 8; ++n0) {
    if (n0 < 7) LOADN(n0 + 1);                 // issue next-tile loads early
    const int d = n0 * 16 + lm;
    short4 cts = *(const short4*)&Cafr[cbase + (size_t)n0 * 64 * 512];  // bf16 ct
    const char* bq = Bst + (n0 & 1) * 16384 + lm * 512;
    f32x4 cA = {0.f, 0.f, 0.f, 0.f};
    f32x4 cB = {0.f, 0.f, 0.f, 0.f};
#pragma unroll
    for (int kk = 0; kk < 8; ++kk) {
      const int so = (((kk * 4 + lk) ^ (lm & 7)) << 4);
      cA = MFMA16(afr[kk], *(const bf16x8*)(bq + so), cA);
      cB = MFMA16(afr[kk], *(const bf16x8*)(bq + 8192 + so), cB);
    }
    if (n0 < 7) {
      WRITEN((n0 + 1) & 1);                    // write-late into other buffer
      __syncthreads();
    }
    float4 ct;
    ct.x = bf2f(cts.x); ct.y = bf2f(cts.y); ct.z = bf2f(cts.z); ct.w = bf2f(cts.w);
    float4 av, ca, cb;
    av.x = cA[0] * invr[0]; av.y = cA[1] * invr[1];
    av.z = cA[2] * invr[2]; av.w = cA[3] * invr[3];
    ca.x = ct.x * av.x; ca.y = ct.y * av.y; ca.z = ct.z * av.z; ca.w = ct.w * av.w;
    cb.x = ct.x * cB[0] * invr[0]; cb.y = ct.y * cB[1] * invr[1];
    cb.z = ct.z * cB[2] * invr[2]; cb.w = ct.w * cB[3] * invr[3];
    float* o0 = ob + (size_t)d * NLC + iB;
    *(float4*)o0 = ct;
    *(float4*)(o0 + (size_t)128 * NLC) = av;
    *(float4*)(o0 + (size_t)256 * NLC) = ca;
    *(float4*)(o0 + (size_t)384 * NLC) = cb;
  }
#undef LOADN
#undef WRITEN
}

// ---------------------------------------------------------------------------
extern "C" void kernel_launch(void* const* d_in, const int* in_sizes, int n_in,
                              void* d_out, int out_size, void* d_ws, size_t ws_size,
                              hipStream_t stream) {
  const float* C = (const float*)d_in[0];
  const float* Q = (const float*)d_in[1];
  const int* Cmask = (const int*)d_in[2];
  const int* Qmask = (const int*)d_in[3];
  const float* w4C = (const float*)d_in[4];
  const float* w4Q = (const float*)d_in[5];
  const float* w4mlu = (const float*)d_in[6];
  const float* bias = (const float*)d_in[7];
  float* out = (float*)d_out;

  short* Cfr = (short*)d_ws;                           // [b][128 tiles][4][64][8]
  short* Cafr = Cfr + (size_t)NB * NLC * ND;           // [b][8 dt][64 ic][64][8]
  short* Qfr = Cafr + (size_t)NB * NLC * ND;           // [b][16 tiles][4][64][8] (w4mlu folded)
  short* Qbf = Qfr + (size_t)NB * NLQ * ND;            // [b][D][Lq]
  short* MTbf = Qbf + (size_t)NB * NLQ * ND;           // [b][D][Lq]
  short* E = MTbf + (size_t)NB * ND * NLQ;             // [b][128 it][8 kk][64][8]
  short* mskE = E + (size_t)NB * NLC * NLQ;            // [b][256]
  float* cq = (float*)(mskE + (size_t)NB * NLQ);
  float* qq = cq + NB * NLC;
  size_t need = (size_t)(qq + NB * NLQ - (float*)d_ws) * sizeof(float);
  if (ws_size < need) return;  // fail loudly rather than corrupt

  hipMemsetAsync(cq, 0, (size_t)(NB * NLC + NB * NLQ) * sizeof(float), stream);
  k_tr<<<dim3(NLC / 64, ND / 32, NB), 256, 0, stream>>>(C, nullptr, w4C, Cfr, Cafr, cq, NLC, 1, nullptr, nullptr);
  k_tr<<<dim3(NLQ / 64, ND / 32, NB), 256, 0, stream>>>(Q, w4mlu, w4Q, Qfr, Qbf, qq, NLQ, 0, Qmask, mskE);
  k_MT<<<256, 512, 0, stream>>>(Cfr, Qfr, Cafr, Cmask, cq, qq, bias, MTbf, E);
  k_PAB<<<1024, 256, 0, stream>>>(Cafr, E, mskE, Qbf, MTbf, out);
}

// Round 18
// 82.765 us; speedup vs baseline: 1.8138x; 1.1343x over previous
//
#include <hip/hip_runtime.h>
#include <cstdint>

// CQAttention: B=32, D=128, Lc=2048, Lq=256, f32 in/out.
// Pipeline (R18): 3 launches.
//   k_tr    : MERGED C+Q pass (grid x<32: C, else Q). bf16 fragment-major
//             copies (Cfr/Qfr R15, Cafr R16, Qbf natural), mskE build,
//             and per-y-slice partial dots cqp/qqp (plain stores - memset
//             and atomics eliminated; k_MT sums the 4 slices).
//   k_MT    : R18: 1024 thr / 16 waves (was 512/8, 25% occupancy, 1
//             block/CU - latency-starved). S^T: wave (qsub,ioct) 1 tile/
//             iter. MT GEMM: wave (wd,wh) splits ks; wh-halves summed via
//             16KB LDS at end. Also writes unmasked E (R17) + MTbf.
//   k_PAB   : A/Bt GEMMs from E (R17), LDS B-panel staging (R12), Cafr ct
//             stream (R16). Unchanged.
// Bt = S1 @ (S2^T @ Ct) associativity rewrite avoids the Lc x Lc matrix.

#define NB 32
#define ND 128
#define NLC 2048
#define NLQ 256
#define FNEG (-1.0e30f)
#define ESHIFT 20.0f

typedef __attribute__((ext_vector_type(8))) short bf16x8;
typedef __attribute__((ext_vector_type(4))) float f32x4;
#define MFMA16(a, b, c) __builtin_amdgcn_mfma_f32_16x16x32_bf16(a, b, c, 0, 0, 0)

__device__ __forceinline__ short f2bf(float x) {
  union { float f; unsigned u; } v; v.f = x;
  unsigned r = (v.u + 0x7FFFu + ((v.u >> 16) & 1u)) >> 16;
  return (short)r;
}
__device__ __forceinline__ float bf2f(short x) {
  union { unsigned u; float f; } v; v.u = ((unsigned)(unsigned short)x) << 16;
  return v.f;
}

// ------- merged C/Q pass: fragment-major copies + partial dots + mskE ------
__global__ __launch_bounds__(256) void k_tr(const float* __restrict__ C,
                                            const float* __restrict__ Q,
                                            const float* __restrict__ w4C,
                                            const float* __restrict__ w4Q,
                                            const float* __restrict__ w4mlu,
                                            short* __restrict__ Cfr,
                                            short* __restrict__ Cafr,
                                            short* __restrict__ Qfr,
                                            short* __restrict__ Qbf,
                                            float* __restrict__ cqp,
                                            float* __restrict__ qqp,
                                            const int* __restrict__ Qmask,
                                            short* __restrict__ mskE) {
  __shared__ float T[32][66];
  const int b = blockIdx.z, d0 = blockIdx.y * 32;
  const int t = threadIdx.x;
  const bool isC = blockIdx.x < 32;
  const int i0 = (isC ? blockIdx.x : (blockIdx.x - 32)) * 64;
  const int L = isC ? NLC : NLQ;
  const float* in = isC ? C : Q;
#pragma unroll
  for (int rr = 0; rr < 2; ++rr) {
    int idx = t + rr * 256;
    int dd = idx >> 4, c4 = idx & 15;
    const float* src = in + ((size_t)b * ND + d0 + dd) * L + i0 + c4 * 4;
    float4 v = *(const float4*)src;
    T[dd][c4 * 4 + 0] = v.x;
    T[dd][c4 * 4 + 1] = v.y;
    T[dd][c4 * 4 + 2] = v.z;
    T[dd][c4 * 4 + 3] = v.w;
    if (!isC) {  // Q natural bf16 copy for k_PAB's B-panel staging
      short4 o;
      o.x = f2bf(v.x); o.y = f2bf(v.y); o.z = f2bf(v.z); o.w = f2bf(v.w);
      *(short4*)(Qbf + ((size_t)b * ND + d0 + dd) * L + i0 + c4 * 4) = o;
    }
  }
  __syncthreads();
  // partial dot for this d0 slice (plain store, summed in k_MT)
  if (t < 64) {
    const float* wd_ = isC ? w4C : w4Q;
    float s = 0.f;
#pragma unroll
    for (int dd = 0; dd < 32; ++dd) s = fmaf(T[dd][t], wd_[d0 + dd], s);
    (isC ? cqp : qqp)[((size_t)blockIdx.y * NB + b) * L + i0 + t] = s;
  }
  if (!isC && blockIdx.y == 0 && t < 64) {
    const int j = i0 + t;
    mskE[(size_t)b * NLQ + j] = Qmask[b * NLQ + j] ? (short)0xFFFF : (short)0;
  }
  if (isC) {  // MT-A fragment-major store (Cafr)
    const int dt_loc = t & 1, ic_loc = (t >> 1) & 1, lane = t >> 2;
    const int dd = dt_loc * 16 + (lane & 15);
    const int ibase = ic_loc * 32 + ((lane >> 4) & 3) * 8;
    bf16x8 pk;
#pragma unroll
    for (int k = 0; k < 8; ++k) pk[k] = f2bf(T[dd][ibase + k]);
    const size_t dtile = (size_t)((d0 >> 4) + dt_loc);
    const size_t ichunk = (size_t)((i0 >> 5) + ic_loc);
    *(bf16x8*)(Cafr + (((size_t)b * 8 + dtile) * (size_t)(NLC >> 5) + ichunk) * 512 +
               (size_t)lane * 8) = pk;
  }
  // fragment-major transposed store (Cfr / Qfr, w4mlu folded on Q)
  const int i = t >> 2, seg = t & 3;
  bf16x8 pack;
#pragma unroll
  for (int k = 0; k < 8; ++k) {
    int d = seg * 8 + k;
    float x = T[d][i];
    if (!isC) x *= w4mlu[d0 + d];
    pack[k] = f2bf(x);
  }
  {
    const size_t tile = (size_t)((i0 + i) >> 4);
    const int lane = seg * 16 + ((i0 + i) & 15);
    *(bf16x8*)((isC ? Cfr : Qfr) + ((size_t)b * (L >> 4) + tile) * 2048 +
               (size_t)(d0 >> 5) * 512 + (size_t)lane * 8) = pack;
  }
}

// ---------------- k_MT: MT GEMM + E materialization, 16 waves --------------
// 1D grid 256 blocks (8 XCD x 32), 1024 thr (16 waves -> 50% occupancy).
// S^T: wave (qsub=w&1, ioct=w>>1) computes 1 tile/i0-iter.
// MT GEMM: wave (wd=w&7, wh=w>>3) does ks in {wh*2, wh*2+1}; halves summed
// via mtred LDS after the loop.
__global__ __launch_bounds__(1024) void k_MT(const short* __restrict__ Cfr,
                                             const short* __restrict__ Qfr,
                                             const short* __restrict__ Cafr,
                                             const int* __restrict__ Cmask,
                                             const float* __restrict__ cqp,
                                             const float* __restrict__ qqp,
                                             const float* __restrict__ bias,
                                             short* __restrict__ MTbf,
                                             short* __restrict__ E) {
  __shared__ short PTs[32 * 136];      // P2^T bf16 [q 32][i-chunk 128]
  __shared__ float cspart[16][32];
  __shared__ float bc[32];
  __shared__ float mtred[8][2][64][4]; // wh=1 partial accMT (16KB)
  const int flat = blockIdx.x;                 // 256 = 8*32 exactly
  const int swz = (flat & 7) * 32 + (flat >> 3);
  const int b = swz >> 3, qt = (swz & 7) * 32;
  const int tid = threadIdx.x;
  const int w = tid >> 6, l = tid & 63, lm = l & 15, lk = l >> 4;
  const int qsub = w & 1, ioct = w >> 1;
  const int wd = w & 7, wh = w >> 3;
  const float bv = bias[0];

  bf16x8 aq[4];
  {
    const short* Qf = Qfr + ((size_t)b * 16 + (qt >> 4) + qsub) * 2048 + (size_t)l * 8;
#pragma unroll
    for (int kk = 0; kk < 4; ++kk) aq[kk] = *(const bf16x8*)(Qf + kk * 512);
  }
  float qqv[4];
#pragma unroll
  for (int r = 0; r < 4; ++r) {
    const size_t j = (size_t)b * NLQ + qt + qsub * 16 + lk * 4 + r;
    qqv[r] = qqp[j] + qqp[(size_t)NB * NLQ + j] + qqp[2 * (size_t)NB * NLQ + j] +
             qqp[3 * (size_t)NB * NLQ + j] + bv;
  }

  const int elane = (qsub * 2 + (lk >> 1)) * 16 + lm;
  short* Eb = E + (size_t)b * 128 * 4096 + (size_t)(qt >> 5) * 512 +
              (size_t)elane * 8 + (lk & 1) * 4;

  float csacc[4] = {0.f, 0.f, 0.f, 0.f};
  f32x4 accMT[2] = {{0.f, 0.f, 0.f, 0.f}, {0.f, 0.f, 0.f, 0.f}};
  for (int i0 = 0; i0 < NLC; i0 += 128) {
    {
      const int iCol = i0 + ioct * 16 + lm;
      const short* Cf = Cfr + ((size_t)b * 128 + (i0 >> 4) + ioct) * 2048 + (size_t)l * 8;
      f32x4 c = {0.f, 0.f, 0.f, 0.f};
#pragma unroll
      for (int kk = 0; kk < 4; ++kk)
        c = MFMA16(aq[kk], *(const bf16x8*)(Cf + kk * 512), c);
      const size_t ci = (size_t)b * NLC + iCol;
      const float cqb = cqp[ci] + cqp[(size_t)NB * NLC + ci] +
                        cqp[2 * (size_t)NB * NLC + ci] + cqp[3 * (size_t)NB * NLC + ci];
      const int cm = Cmask[b * NLC + iCol];
      short ev[4];
#pragma unroll
      for (int r = 0; r < 4; ++r) {
        float s = c[r] + cqb + qqv[r];
        float pu = __expf(s - ESHIFT);       // unmasked -> E
        float pm = cm ? pu : 0.f;            // Cmask-masked -> PTs/colsum
        csacc[r] += pm;
        PTs[(qsub * 16 + lk * 4 + r) * 136 + ioct * 16 + lm] = f2bf(pm);
        ev[r] = f2bf(pu);
      }
      *(short4*)(Eb + (size_t)((i0 >> 4) + ioct) * 4096) = *(short4*)ev;
    }
    __syncthreads();
    // MT GEMM: A[m=d]=Cafr fragment-major, B=P^T from LDS; ks split by wh
    const short* Arow = Cafr + (((size_t)b * 8 + wd) * 64 + (i0 >> 5)) * 512 + (size_t)l * 8;
#pragma unroll
    for (int ks2 = 0; ks2 < 2; ++ks2) {
      const int ks = wh * 2 + ks2;
      bf16x8 a = *(const bf16x8*)(Arow + ks * 512);
#pragma unroll
      for (int qs = 0; qs < 2; ++qs) {
        bf16x8 bb = *(const bf16x8*)&PTs[(qs * 16 + lm) * 136 + ks * 32 + lk * 8];
        accMT[qs] = MFMA16(a, bb, accMT[qs]);
      }
    }
    __syncthreads();
  }
  // stash wh=1 partial accMT
  if (wh == 1) {
#pragma unroll
    for (int qs = 0; qs < 2; ++qs)
#pragma unroll
      for (int r = 0; r < 4; ++r) mtred[wd][qs][l][r] = accMT[qs][r];
  }
  // colsum reduce (all 16 waves)
#pragma unroll
  for (int off = 1; off < 16; off <<= 1)
#pragma unroll
    for (int r = 0; r < 4; ++r) csacc[r] += __shfl_xor(csacc[r], off, 64);
  if (lm == 0) {
#pragma unroll
    for (int r = 0; r < 4; ++r) cspart[w][qsub * 16 + lk * 4 + r] = csacc[r];
  }
  __syncthreads();
  if (tid < 32) {
    const int base = (tid >> 4) & 1;
    float s = 0.f;
#pragma unroll
    for (int k2 = 0; k2 < 8; ++k2) s += cspart[k2 * 2 + base][tid];
    bc[tid] = 1.0f / s;
  }
  __syncthreads();
  if (wh == 0) {
#pragma unroll
    for (int qs = 0; qs < 2; ++qs) {
#pragma unroll
      for (int r = 0; r < 4; ++r) accMT[qs][r] += mtred[wd][qs][l][r];
      const float inv = bc[qs * 16 + lm];
#pragma unroll
      for (int r = 0; r < 4; ++r)
        MTbf[((size_t)b * ND + wd * 16 + lk * 4 + r) * NLQ + qt + qs * 16 + lm] =
            f2bf(accMT[qs][r] * inv);
    }
  }
}

// ---------------- k_PAB: A/Bt GEMMs from E, LDS B-staging ------------------
// 1D grid 1024 blocks (XCD-bijective swizzle). 256 thr (4 waves). Unchanged.
__global__ __launch_bounds__(256) void k_PAB(const short* __restrict__ Cafr,
                                             const short* __restrict__ E,
                                             const short* __restrict__ mskE,
                                             const short* __restrict__ Qbf,
                                             const short* __restrict__ MTbf,
                                             float* __restrict__ out) {
  __shared__ __align__(16) char Bst[32768];    // 2x16KB B-stage
  const int flat = blockIdx.x;                 // 1024 = 8*128 exactly
  const int swz = (flat & 7) * 128 + (flat >> 3);
  const int b = swz >> 5, it = (swz & 31) * 64;
  const int tid = threadIdx.x;
  const int wi = tid >> 6, l = tid & 63, lm = l & 15, lk = l >> 4;

  // ---- afr from E (Qmask via AND), rowsum via shfl ----
  bf16x8 afr[8];
  {
    const short* Ef = E + ((size_t)b * 128 + (it >> 4) + wi) * 4096 + (size_t)l * 8;
    const short* mb = mskE + (size_t)b * NLQ + lk * 8;
#pragma unroll
    for (int kk = 0; kk < 8; ++kk) {
      bf16x8 a = *(const bf16x8*)(Ef + kk * 512);
      bf16x8 m = *(const bf16x8*)(mb + kk * 32);
      afr[kk] = a & m;
    }
  }
  float rsum = 0.f;
#pragma unroll
  for (int kk = 0; kk < 8; ++kk)
#pragma unroll
    for (int e = 0; e < 8; ++e) rsum += bf2f(afr[kk][e]);
  rsum += __shfl_xor(rsum, 16, 64);
  rsum += __shfl_xor(rsum, 32, 64);
  float invr[4];
#pragma unroll
  for (int r = 0; r < 4; ++r)
    invr[r] = 1.0f / __shfl(rsum, (l & 48) + lk * 4 + r, 64);

  // ---- phase 2: double-buffered B-panel staging + MFMA + direct stores ----
  const short* Qp = Qbf + (size_t)b * ND * NLQ;
  const short* Mp = MTbf + (size_t)b * ND * NLQ;
  float* ob = out + (size_t)b * 4 * ND * NLC;
  const int iB = it + wi * 16 + lk * 4;
  const size_t cbase = ((size_t)b * 8 * 64 + (size_t)(iB >> 5)) * 512 +
                       (size_t)(((iB >> 3) & 3) * 16 + lm) * 8 + (size_t)(iB & 7);

  const int srow = tid >> 4, scol = tid & 15;
  const int wsw0 = (((scol * 2) ^ (srow & 7)) << 4);
  const int wsw1 = (((scol * 2 + 1) ^ (srow & 7)) << 4);
  const short* qsrc = Qp + (size_t)srow * NLQ + scol * 16;
  const short* msrc = Mp + (size_t)srow * NLQ + scol * 16;
  bf16x8 sq0, sq1, sm0, sm1;

#define LOADN(n0) { \
    const short* q_ = qsrc + (size_t)(n0) * 16 * NLQ; \
    const short* m_ = msrc + (size_t)(n0) * 16 * NLQ; \
    sq0 = *(const bf16x8*)q_;  sq1 = *(const bf16x8*)(q_ + 8); \
    sm0 = *(const bf16x8*)m_;  sm1 = *(const bf16x8*)(m_ + 8); }
#define WRITEN(buf) { \
    char* base_ = Bst + (buf) * 16384 + srow * 512; \
    *(bf16x8*)(base_ + wsw0) = sq0; *(bf16x8*)(base_ + wsw1) = sq1; \
    *(bf16x8*)(base_ + 8192 + wsw0) = sm0; *(bf16x8*)(base_ + 8192 + wsw1) = sm1; }

  LOADN(0); WRITEN(0);
  __syncthreads();
#pragma unroll
  for (int n0 = 0; n0 < 8; ++n0) {
    if (n0 < 7) LOADN(n0 + 1);                 // issue next-tile loads early
    const int d = n0 * 16 + lm;
    short4 cts = *(const short4*)&Cafr[cbase + (size_t)n0 * 64 * 512];  // bf16 ct
    const char* bq = Bst + (n0 & 1) * 16384 + lm * 512;
    f32x4 cA = {0.f, 0.f, 0.f, 0.f};
    f32x4 cB = {0.f, 0.f, 0.f, 0.f};
#pragma unroll
    for (int kk = 0; kk < 8; ++kk) {
      const int so = (((kk * 4 + lk) ^ (lm & 7)) << 4);
      cA = MFMA16(afr[kk], *(const bf16x8*)(bq + so), cA);
      cB = MFMA16(afr[kk], *(const bf16x8*)(bq + 8192 + so), cB);
    }
    if (n0 < 7) {
      WRITEN((n0 + 1) & 1);                    // write-late into other buffer
      __syncthreads();
    }
    float4 ct;
    ct.x = bf2f(cts.x); ct.y = bf2f(cts.y); ct.z = bf2f(cts.z); ct.w = bf2f(cts.w);
    float4 av, ca, cb;
    av.x = cA[0] * invr[0]; av.y = cA[1] * invr[1];
    av.z = cA[2] * invr[2]; av.w = cA[3] * invr[3];
    ca.x = ct.x * av.x; ca.y = ct.y * av.y; ca.z = ct.z * av.z; ca.w = ct.w * av.w;
    cb.x = ct.x * cB[0] * invr[0]; cb.y = ct.y * cB[1] * invr[1];
    cb.z = ct.z * cB[2] * invr[2]; cb.w = ct.w * cB[3] * invr[3];
    float* o0 = ob + (size_t)d * NLC + iB;
    *(float4*)o0 = ct;
    *(float4*)(o0 + (size_t)128 * NLC) = av;
    *(float4*)(o0 + (size_t)256 * NLC) = ca;
    *(float4*)(o0 + (size_t)384 * NLC) = cb;
  }
#undef LOADN
#undef WRITEN
}

// ---------------------------------------------------------------------------
extern "C" void kernel_launch(void* const* d_in, const int* in_sizes, int n_in,
                              void* d_out, int out_size, void* d_ws, size_t ws_size,
                              hipStream_t stream) {
  const float* C = (const float*)d_in[0];
  const float* Q = (const float*)d_in[1];
  const int* Cmask = (const int*)d_in[2];
  const int* Qmask = (const int*)d_in[3];
  const float* w4C = (const float*)d_in[4];
  const float* w4Q = (const float*)d_in[5];
  const float* w4mlu = (const float*)d_in[6];
  const float* bias = (const float*)d_in[7];
  float* out = (float*)d_out;

  short* Cfr = (short*)d_ws;                           // [b][128 tiles][4][64][8]
  short* Cafr = Cfr + (size_t)NB * NLC * ND;           // [b][8 dt][64 ic][64][8]
  short* Qfr = Cafr + (size_t)NB * NLC * ND;           // [b][16 tiles][4][64][8] (w4mlu folded)
  short* Qbf = Qfr + (size_t)NB * NLQ * ND;            // [b][D][Lq]
  short* MTbf = Qbf + (size_t)NB * NLQ * ND;           // [b][D][Lq]
  short* E = MTbf + (size_t)NB * ND * NLQ;             // [b][128 it][8 kk][64][8]
  short* mskE = E + (size_t)NB * NLC * NLQ;            // [b][256]
  float* cqp = (float*)(mskE + (size_t)NB * NLQ);      // [4][b][Lc] partials
  float* qqp = cqp + 4 * (size_t)NB * NLC;             // [4][b][Lq] partials
  size_t need = (size_t)(qqp + 4 * NB * NLQ - (float*)d_ws) * sizeof(float);
  if (ws_size < need) return;  // fail loudly rather than corrupt

  k_tr<<<dim3(36, 4, NB), 256, 0, stream>>>(C, Q, w4C, w4Q, w4mlu, Cfr, Cafr, Qfr, Qbf,
                                            cqp, qqp, Qmask, mskE);
  k_MT<<<256, 1024, 0, stream>>>(Cfr, Qfr, Cafr, Cmask, cqp, qqp, bias, MTbf, E);
  k_PAB<<<1024, 256, 0, stream>>>(Cafr, E, mskE, Qbf, MTbf, out);
}

// Round 19
// 75.060 us; speedup vs baseline: 2.0000x; 1.1027x over previous
//
#include <hip/hip_runtime.h>
#include <cstdint>

// CQAttention: B=32, D=128, Lc=2048, Lq=256, f32 in/out.
// Pipeline (R19): 3 launches.
//   k_tr    : merged C+Q pass: fragment-major copies (Cfr/Qfr/Cafr), Qbf,
//             mskE, partial dots. R19: also writes out stream 0 (Ct) as
//             exact f32 (coalesced; removes that store from k_PAB's loop).
//   k_MT    : 1024 thr / 16 waves. R19: PTs double-buffered -> ONE barrier
//             per i0-iter (was 2); MT-A frags + next Cf loads issued before
//             the barrier (latency hides under barrier wait). Writes
//             unmasked E + MTbf.
//   k_PAB   : A/Bt GEMMs from E, LDS B-panel staging. R19: 8 ct loads
//             hoisted above the loop; 3 stores/iter (Ct stream moved to
//             k_tr).
// Bt = S1 @ (S2^T @ Ct) associativity rewrite avoids the Lc x Lc matrix.

#define NB 32
#define ND 128
#define NLC 2048
#define NLQ 256
#define FNEG (-1.0e30f)
#define ESHIFT 20.0f

typedef __attribute__((ext_vector_type(8))) short bf16x8;
typedef __attribute__((ext_vector_type(4))) float f32x4;
#define MFMA16(a, b, c) __builtin_amdgcn_mfma_f32_16x16x32_bf16(a, b, c, 0, 0, 0)

__device__ __forceinline__ short f2bf(float x) {
  union { float f; unsigned u; } v; v.f = x;
  unsigned r = (v.u + 0x7FFFu + ((v.u >> 16) & 1u)) >> 16;
  return (short)r;
}
__device__ __forceinline__ float bf2f(short x) {
  union { unsigned u; float f; } v; v.u = ((unsigned)(unsigned short)x) << 16;
  return v.f;
}

// ------- merged C/Q pass: fragment-major copies + partial dots + mskE ------
// R19: C blocks also write out stream 0 (Ct, exact f32).
__global__ __launch_bounds__(256) void k_tr(const float* __restrict__ C,
                                            const float* __restrict__ Q,
                                            const float* __restrict__ w4C,
                                            const float* __restrict__ w4Q,
                                            const float* __restrict__ w4mlu,
                                            short* __restrict__ Cfr,
                                            short* __restrict__ Cafr,
                                            short* __restrict__ Qfr,
                                            short* __restrict__ Qbf,
                                            float* __restrict__ cqp,
                                            float* __restrict__ qqp,
                                            const int* __restrict__ Qmask,
                                            short* __restrict__ mskE,
                                            float* __restrict__ out) {
  __shared__ float T[32][66];
  const int b = blockIdx.z, d0 = blockIdx.y * 32;
  const int t = threadIdx.x;
  const bool isC = blockIdx.x < 32;
  const int i0 = (isC ? blockIdx.x : (blockIdx.x - 32)) * 64;
  const int L = isC ? NLC : NLQ;
  const float* in = isC ? C : Q;
#pragma unroll
  for (int rr = 0; rr < 2; ++rr) {
    int idx = t + rr * 256;
    int dd = idx >> 4, c4 = idx & 15;
    const float* src = in + ((size_t)b * ND + d0 + dd) * L + i0 + c4 * 4;
    float4 v = *(const float4*)src;
    T[dd][c4 * 4 + 0] = v.x;
    T[dd][c4 * 4 + 1] = v.y;
    T[dd][c4 * 4 + 2] = v.z;
    T[dd][c4 * 4 + 3] = v.w;
    if (!isC) {  // Q natural bf16 copy for k_PAB's B-panel staging
      short4 o;
      o.x = f2bf(v.x); o.y = f2bf(v.y); o.z = f2bf(v.z); o.w = f2bf(v.w);
      *(short4*)(Qbf + ((size_t)b * ND + d0 + dd) * L + i0 + c4 * 4) = o;
    } else {     // out stream 0 = Ct, exact f32
      *(float4*)(out + ((size_t)b * 4 * ND + d0 + dd) * NLC + i0 + c4 * 4) = v;
    }
  }
  __syncthreads();
  // partial dot for this d0 slice (plain store, summed in k_MT)
  if (t < 64) {
    const float* wd_ = isC ? w4C : w4Q;
    float s = 0.f;
#pragma unroll
    for (int dd = 0; dd < 32; ++dd) s = fmaf(T[dd][t], wd_[d0 + dd], s);
    (isC ? cqp : qqp)[((size_t)blockIdx.y * NB + b) * L + i0 + t] = s;
  }
  if (!isC && blockIdx.y == 0 && t < 64) {
    const int j = i0 + t;
    mskE[(size_t)b * NLQ + j] = Qmask[b * NLQ + j] ? (short)0xFFFF : (short)0;
  }
  if (isC) {  // MT-A fragment-major store (Cafr)
    const int dt_loc = t & 1, ic_loc = (t >> 1) & 1, lane = t >> 2;
    const int dd = dt_loc * 16 + (lane & 15);
    const int ibase = ic_loc * 32 + ((lane >> 4) & 3) * 8;
    bf16x8 pk;
#pragma unroll
    for (int k = 0; k < 8; ++k) pk[k] = f2bf(T[dd][ibase + k]);
    const size_t dtile = (size_t)((d0 >> 4) + dt_loc);
    const size_t ichunk = (size_t)((i0 >> 5) + ic_loc);
    *(bf16x8*)(Cafr + (((size_t)b * 8 + dtile) * (size_t)(NLC >> 5) + ichunk) * 512 +
               (size_t)lane * 8) = pk;
  }
  // fragment-major transposed store (Cfr / Qfr, w4mlu folded on Q)
  const int i = t >> 2, seg = t & 3;
  bf16x8 pack;
#pragma unroll
  for (int k = 0; k < 8; ++k) {
    int d = seg * 8 + k;
    float x = T[d][i];
    if (!isC) x *= w4mlu[d0 + d];
    pack[k] = f2bf(x);
  }
  {
    const size_t tile = (size_t)((i0 + i) >> 4);
    const int lane = seg * 16 + ((i0 + i) & 15);
    *(bf16x8*)((isC ? Cfr : Qfr) + ((size_t)b * (L >> 4) + tile) * 2048 +
               (size_t)(d0 >> 5) * 512 + (size_t)lane * 8) = pack;
  }
}

// ---------------- k_MT: MT GEMM + E materialization, 16 waves --------------
// 1D grid 256 blocks (8 XCD x 32), 1024 thr. R19: double-buffered PTs ->
// one barrier per i0-iter; A-frags + next-Cf loads issued pre-barrier.
__global__ __launch_bounds__(1024) void k_MT(const short* __restrict__ Cfr,
                                             const short* __restrict__ Qfr,
                                             const short* __restrict__ Cafr,
                                             const int* __restrict__ Cmask,
                                             const float* __restrict__ cqp,
                                             const float* __restrict__ qqp,
                                             const float* __restrict__ bias,
                                             short* __restrict__ MTbf,
                                             short* __restrict__ E) {
  __shared__ short PTs[2][32 * 136];   // double-buffered P2^T bf16
  __shared__ float cspart[16][32];
  __shared__ float bc[32];
  __shared__ float mtred[8][2][64][4]; // wh=1 partial accMT (16KB)
  const int flat = blockIdx.x;                 // 256 = 8*32 exactly
  const int swz = (flat & 7) * 32 + (flat >> 3);
  const int b = swz >> 3, qt = (swz & 7) * 32;
  const int tid = threadIdx.x;
  const int w = tid >> 6, l = tid & 63, lm = l & 15, lk = l >> 4;
  const int qsub = w & 1, ioct = w >> 1;
  const int wd = w & 7, wh = w >> 3;
  const float bv = bias[0];

  bf16x8 aq[4];
  {
    const short* Qf = Qfr + ((size_t)b * 16 + (qt >> 4) + qsub) * 2048 + (size_t)l * 8;
#pragma unroll
    for (int kk = 0; kk < 4; ++kk) aq[kk] = *(const bf16x8*)(Qf + kk * 512);
  }
  float qqv[4];
#pragma unroll
  for (int r = 0; r < 4; ++r) {
    const size_t j = (size_t)b * NLQ + qt + qsub * 16 + lk * 4 + r;
    qqv[r] = qqp[j] + qqp[(size_t)NB * NLQ + j] + qqp[2 * (size_t)NB * NLQ + j] +
             qqp[3 * (size_t)NB * NLQ + j] + bv;
  }

  const int elane = (qsub * 2 + (lk >> 1)) * 16 + lm;
  short* Eb = E + (size_t)b * 128 * 4096 + (size_t)(qt >> 5) * 512 +
              (size_t)elane * 8 + (lk & 1) * 4;

  // preload first Cf tile
  bf16x8 cf[4];
  {
    const short* Cf0 = Cfr + ((size_t)b * 128 + ioct) * 2048 + (size_t)l * 8;
#pragma unroll
    for (int kk = 0; kk < 4; ++kk) cf[kk] = *(const bf16x8*)(Cf0 + kk * 512);
  }

  float csacc[4] = {0.f, 0.f, 0.f, 0.f};
  f32x4 accMT[2] = {{0.f, 0.f, 0.f, 0.f}, {0.f, 0.f, 0.f, 0.f}};
  for (int i0 = 0, it = 0; i0 < NLC; i0 += 128, ++it) {
    const int p = it & 1;
    short* PT = PTs[p];
    {
      const int iCol = i0 + ioct * 16 + lm;
      f32x4 c = {0.f, 0.f, 0.f, 0.f};
#pragma unroll
      for (int kk = 0; kk < 4; ++kk) c = MFMA16(aq[kk], cf[kk], c);
      const size_t ci = (size_t)b * NLC + iCol;
      const float cqb = cqp[ci] + cqp[(size_t)NB * NLC + ci] +
                        cqp[2 * (size_t)NB * NLC + ci] + cqp[3 * (size_t)NB * NLC + ci];
      const int cm = Cmask[b * NLC + iCol];
      short ev[4];
#pragma unroll
      for (int r = 0; r < 4; ++r) {
        float s = c[r] + cqb + qqv[r];
        float pu = __expf(s - ESHIFT);       // unmasked -> E
        float pm = cm ? pu : 0.f;            // Cmask-masked -> PTs/colsum
        csacc[r] += pm;
        PT[(qsub * 16 + lk * 4 + r) * 136 + ioct * 16 + lm] = f2bf(pm);
        ev[r] = f2bf(pu);
      }
      *(short4*)(Eb + (size_t)((i0 >> 4) + ioct) * 4096) = *(short4*)ev;
    }
    // MT-A frags for THIS iter (independent of PTs) - issue pre-barrier
    bf16x8 a4[2];
    {
      const short* Arow = Cafr + (((size_t)b * 8 + wd) * 64 + (i0 >> 5)) * 512 +
                          (size_t)(wh * 2) * 512 + (size_t)l * 8;
      a4[0] = *(const bf16x8*)Arow;
      a4[1] = *(const bf16x8*)(Arow + 512);
    }
    // next iter's Cf - issue pre-barrier
    if (i0 + 128 < NLC) {
      const short* Cfn = Cfr + ((size_t)b * 128 + (i0 >> 4) + 8 + ioct) * 2048 + (size_t)l * 8;
#pragma unroll
      for (int kk = 0; kk < 4; ++kk) cf[kk] = *(const bf16x8*)(Cfn + kk * 512);
    }
    __syncthreads();
    // MT GEMM: ks split by wh
#pragma unroll
    for (int ks2 = 0; ks2 < 2; ++ks2) {
      const int ks = wh * 2 + ks2;
#pragma unroll
      for (int qs = 0; qs < 2; ++qs) {
        bf16x8 bb = *(const bf16x8*)&PT[(qs * 16 + lm) * 136 + ks * 32 + lk * 8];
        accMT[qs] = MFMA16(a4[ks2], bb, accMT[qs]);
      }
    }
  }
  __syncthreads();
  // stash wh=1 partial accMT
  if (wh == 1) {
#pragma unroll
    for (int qs = 0; qs < 2; ++qs)
#pragma unroll
      for (int r = 0; r < 4; ++r) mtred[wd][qs][l][r] = accMT[qs][r];
  }
  // colsum reduce (all 16 waves)
#pragma unroll
  for (int off = 1; off < 16; off <<= 1)
#pragma unroll
    for (int r = 0; r < 4; ++r) csacc[r] += __shfl_xor(csacc[r], off, 64);
  if (lm == 0) {
#pragma unroll
    for (int r = 0; r < 4; ++r) cspart[w][qsub * 16 + lk * 4 + r] = csacc[r];
  }
  __syncthreads();
  if (tid < 32) {
    const int base = (tid >> 4) & 1;
    float s = 0.f;
#pragma unroll
    for (int k2 = 0; k2 < 8; ++k2) s += cspart[k2 * 2 + base][tid];
    bc[tid] = 1.0f / s;
  }
  __syncthreads();
  if (wh == 0) {
#pragma unroll
    for (int qs = 0; qs < 2; ++qs) {
#pragma unroll
      for (int r = 0; r < 4; ++r) accMT[qs][r] += mtred[wd][qs][l][r];
      const float inv = bc[qs * 16 + lm];
#pragma unroll
      for (int r = 0; r < 4; ++r)
        MTbf[((size_t)b * ND + wd * 16 + lk * 4 + r) * NLQ + qt + qs * 16 + lm] =
            f2bf(accMT[qs][r] * inv);
    }
  }
}

// ---------------- k_PAB: A/Bt GEMMs from E, LDS B-staging ------------------
// 1D grid 1024 blocks (XCD-bijective swizzle). 256 thr (4 waves).
// R19: ct loads hoisted; Ct-stream store moved to k_tr (3 stores/iter).
__global__ __launch_bounds__(256) void k_PAB(const short* __restrict__ Cafr,
                                             const short* __restrict__ E,
                                             const short* __restrict__ mskE,
                                             const short* __restrict__ Qbf,
                                             const short* __restrict__ MTbf,
                                             float* __restrict__ out) {
  __shared__ __align__(16) char Bst[32768];    // 2x16KB B-stage
  const int flat = blockIdx.x;                 // 1024 = 8*128 exactly
  const int swz = (flat & 7) * 128 + (flat >> 3);
  const int b = swz >> 5, it = (swz & 31) * 64;
  const int tid = threadIdx.x;
  const int wi = tid >> 6, l = tid & 63, lm = l & 15, lk = l >> 4;

  // ---- afr from E (Qmask via AND), rowsum via shfl ----
  bf16x8 afr[8];
  {
    const short* Ef = E + ((size_t)b * 128 + (it >> 4) + wi) * 4096 + (size_t)l * 8;
    const short* mb = mskE + (size_t)b * NLQ + lk * 8;
#pragma unroll
    for (int kk = 0; kk < 8; ++kk) {
      bf16x8 a = *(const bf16x8*)(Ef + kk * 512);
      bf16x8 m = *(const bf16x8*)(mb + kk * 32);
      afr[kk] = a & m;
    }
  }
  float rsum = 0.f;
#pragma unroll
  for (int kk = 0; kk < 8; ++kk)
#pragma unroll
    for (int e = 0; e < 8; ++e) rsum += bf2f(afr[kk][e]);
  rsum += __shfl_xor(rsum, 16, 64);
  rsum += __shfl_xor(rsum, 32, 64);
  float invr[4];
#pragma unroll
  for (int r = 0; r < 4; ++r)
    invr[r] = 1.0f / __shfl(rsum, (l & 48) + lk * 4 + r, 64);

  // ---- hoisted ct loads (independent of everything below) ----
  const int iB = it + wi * 16 + lk * 4;
  const size_t cbase = ((size_t)b * 8 * 64 + (size_t)(iB >> 5)) * 512 +
                       (size_t)(((iB >> 3) & 3) * 16 + lm) * 8 + (size_t)(iB & 7);
  short4 cts[8];
#pragma unroll
  for (int n0 = 0; n0 < 8; ++n0)
    cts[n0] = *(const short4*)&Cafr[cbase + (size_t)n0 * 64 * 512];

  // ---- phase 2: double-buffered B-panel staging + MFMA + direct stores ----
  const short* Qp = Qbf + (size_t)b * ND * NLQ;
  const short* Mp = MTbf + (size_t)b * ND * NLQ;
  float* ob = out + (size_t)b * 4 * ND * NLC;

  const int srow = tid >> 4, scol = tid & 15;
  const int wsw0 = (((scol * 2) ^ (srow & 7)) << 4);
  const int wsw1 = (((scol * 2 + 1) ^ (srow & 7)) << 4);
  const short* qsrc = Qp + (size_t)srow * NLQ + scol * 16;
  const short* msrc = Mp + (size_t)srow * NLQ + scol * 16;
  bf16x8 sq0, sq1, sm0, sm1;

#define LOADN(n0) { \
    const short* q_ = qsrc + (size_t)(n0) * 16 * NLQ; \
    const short* m_ = msrc + (size_t)(n0) * 16 * NLQ; \
    sq0 = *(const bf16x8*)q_;  sq1 = *(const bf16x8*)(q_ + 8); \
    sm0 = *(const bf16x8*)m_;  sm1 = *(const bf16x8*)(m_ + 8); }
#define WRITEN(buf) { \
    char* base_ = Bst + (buf) * 16384 + srow * 512; \
    *(bf16x8*)(base_ + wsw0) = sq0; *(bf16x8*)(base_ + wsw1) = sq1; \
    *(bf16x8*)(base_ + 8192 + wsw0) = sm0; *(bf16x8*)(base_ + 8192 + wsw1) = sm1; }

  LOADN(0); WRITEN(0);
  __syncthreads();
#pragma unroll
  for (int n0 = 0; n0 < 8; ++n0) {
    if (n0 < 7) LOADN(n0 + 1);                 // issue next-tile loads early
    const int d = n0 * 16 + lm;
    const char* bq = Bst + (n0 & 1) * 16384 + lm * 512;
    f32x4 cA = {0.f, 0.f, 0.f, 0.f};
    f32x4 cB = {0.f, 0.f, 0.f, 0.f};
#pragma unroll
    for (int kk = 0; kk < 8; ++kk) {
      const int so = (((kk * 4 + lk) ^ (lm & 7)) << 4);
      cA = MFMA16(afr[kk], *(const bf16x8*)(bq + so), cA);
      cB = MFMA16(afr[kk], *(const bf16x8*)(bq + 8192 + so), cB);
    }
    if (n0 < 7) {
      WRITEN((n0 + 1) & 1);                    // write-late into other buffer
      __syncthreads();
    }
    float4 ct;
    ct.x = bf2f(cts[n0].x); ct.y = bf2f(cts[n0].y);
    ct.z = bf2f(cts[n0].z); ct.w = bf2f(cts[n0].w);
    float4 av, ca, cb;
    av.x = cA[0] * invr[0]; av.y = cA[1] * invr[1];
    av.z = cA[2] * invr[2]; av.w = cA[3] * invr[3];
    ca.x = ct.x * av.x; ca.y = ct.y * av.y; ca.z = ct.z * av.z; ca.w = ct.w * av.w;
    cb.x = ct.x * cB[0] * invr[0]; cb.y = ct.y * cB[1] * invr[1];
    cb.z = ct.z * cB[2] * invr[2]; cb.w = ct.w * cB[3] * invr[3];
    float* o0 = ob + (size_t)d * NLC + iB;
    *(float4*)(o0 + (size_t)128 * NLC) = av;
    *(float4*)(o0 + (size_t)256 * NLC) = ca;
    *(float4*)(o0 + (size_t)384 * NLC) = cb;
  }
#undef LOADN
#undef WRITEN
}

// ---------------------------------------------------------------------------
extern "C" void kernel_launch(void* const* d_in, const int* in_sizes, int n_in,
                              void* d_out, int out_size, void* d_ws, size_t ws_size,
                              hipStream_t stream) {
  const float* C = (const float*)d_in[0];
  const float* Q = (const float*)d_in[1];
  const int* Cmask = (const int*)d_in[2];
  const int* Qmask = (const int*)d_in[3];
  const float* w4C = (const float*)d_in[4];
  const float* w4Q = (const float*)d_in[5];
  const float* w4mlu = (const float*)d_in[6];
  const float* bias = (const float*)d_in[7];
  float* out = (float*)d_out;

  short* Cfr = (short*)d_ws;                           // [b][128 tiles][4][64][8]
  short* Cafr = Cfr + (size_t)NB * NLC * ND;           // [b][8 dt][64 ic][64][8]
  short* Qfr = Cafr + (size_t)NB * NLC * ND;           // [b][16 tiles][4][64][8] (w4mlu folded)
  short* Qbf = Qfr + (size_t)NB * NLQ * ND;            // [b][D][Lq]
  short* MTbf = Qbf + (size_t)NB * NLQ * ND;           // [b][D][Lq]
  short* E = MTbf + (size_t)NB * ND * NLQ;             // [b][128 it][8 kk][64][8]
  short* mskE = E + (size_t)NB * NLC * NLQ;            // [b][256]
  float* cqp = (float*)(mskE + (size_t)NB * NLQ);      // [4][b][Lc] partials
  float* qqp = cqp + 4 * (size_t)NB * NLC;             // [4][b][Lq] partials
  size_t need = (size_t)(qqp + 4 * NB * NLQ - (float*)d_ws) * sizeof(float);
  if (ws_size < need) return;  // fail loudly rather than corrupt

  k_tr<<<dim3(36, 4, NB), 256, 0, stream>>>(C, Q, w4C, w4Q, w4mlu, Cfr, Cafr, Qfr, Qbf,
                                            cqp, qqp, Qmask, mskE, out);
  k_MT<<<256, 1024, 0, stream>>>(Cfr, Qfr, Cafr, Cmask, cqp, qqp, bias, MTbf, E);
  k_PAB<<<1024, 256, 0, stream>>>(Cafr, E, mskE, Qbf, MTbf, out);
}

// Round 20
// 72.710 us; speedup vs baseline: 2.0647x; 1.0323x over previous
//
#include <hip/hip_runtime.h>
#include <cstdint>

// CQAttention: B=32, D=128, Lc=2048, Lq=256, f32 in/out.
// Pipeline (R20): 3 launches.
//   k_tr    : merged C+Q pass: fragment-major copies (Cfr/Qfr/Cafr), Qbf,
//             mskE, partial dots, out stream 0 (Ct, exact f32).
//   k_MT    : 1024 thr / 16 waves, double-buffered PTs (1 barrier/iter),
//             pre-barrier A-frag + next-Cf issue. Writes unmasked E + MTbf.
//   k_PAB   : R20: 512 blocks x 512 thr (8 waves, 128 i-rows/block) - B
//             panels staged once per 128 rows instead of 64 (halves L2
//             panel traffic, LDS writes, barriers per unit output). Same
//             proven inner loop (R12 staging, R17 E-afr, R19 hoisted ct).
// Bt = S1 @ (S2^T @ Ct) associativity rewrite avoids the Lc x Lc matrix.

#define NB 32
#define ND 128
#define NLC 2048
#define NLQ 256
#define FNEG (-1.0e30f)
#define ESHIFT 20.0f

typedef __attribute__((ext_vector_type(8))) short bf16x8;
typedef __attribute__((ext_vector_type(4))) float f32x4;
#define MFMA16(a, b, c) __builtin_amdgcn_mfma_f32_16x16x32_bf16(a, b, c, 0, 0, 0)

__device__ __forceinline__ short f2bf(float x) {
  union { float f; unsigned u; } v; v.f = x;
  unsigned r = (v.u + 0x7FFFu + ((v.u >> 16) & 1u)) >> 16;
  return (short)r;
}
__device__ __forceinline__ float bf2f(short x) {
  union { unsigned u; float f; } v; v.u = ((unsigned)(unsigned short)x) << 16;
  return v.f;
}

// ------- merged C/Q pass: fragment-major copies + partial dots + mskE ------
__global__ __launch_bounds__(256) void k_tr(const float* __restrict__ C,
                                            const float* __restrict__ Q,
                                            const float* __restrict__ w4C,
                                            const float* __restrict__ w4Q,
                                            const float* __restrict__ w4mlu,
                                            short* __restrict__ Cfr,
                                            short* __restrict__ Cafr,
                                            short* __restrict__ Qfr,
                                            short* __restrict__ Qbf,
                                            float* __restrict__ cqp,
                                            float* __restrict__ qqp,
                                            const int* __restrict__ Qmask,
                                            short* __restrict__ mskE,
                                            float* __restrict__ out) {
  __shared__ float T[32][66];
  const int b = blockIdx.z, d0 = blockIdx.y * 32;
  const int t = threadIdx.x;
  const bool isC = blockIdx.x < 32;
  const int i0 = (isC ? blockIdx.x : (blockIdx.x - 32)) * 64;
  const int L = isC ? NLC : NLQ;
  const float* in = isC ? C : Q;
#pragma unroll
  for (int rr = 0; rr < 2; ++rr) {
    int idx = t + rr * 256;
    int dd = idx >> 4, c4 = idx & 15;
    const float* src = in + ((size_t)b * ND + d0 + dd) * L + i0 + c4 * 4;
    float4 v = *(const float4*)src;
    T[dd][c4 * 4 + 0] = v.x;
    T[dd][c4 * 4 + 1] = v.y;
    T[dd][c4 * 4 + 2] = v.z;
    T[dd][c4 * 4 + 3] = v.w;
    if (!isC) {  // Q natural bf16 copy for k_PAB's B-panel staging
      short4 o;
      o.x = f2bf(v.x); o.y = f2bf(v.y); o.z = f2bf(v.z); o.w = f2bf(v.w);
      *(short4*)(Qbf + ((size_t)b * ND + d0 + dd) * L + i0 + c4 * 4) = o;
    } else {     // out stream 0 = Ct, exact f32
      *(float4*)(out + ((size_t)b * 4 * ND + d0 + dd) * NLC + i0 + c4 * 4) = v;
    }
  }
  __syncthreads();
  // partial dot for this d0 slice (plain store, summed in k_MT)
  if (t < 64) {
    const float* wd_ = isC ? w4C : w4Q;
    float s = 0.f;
#pragma unroll
    for (int dd = 0; dd < 32; ++dd) s = fmaf(T[dd][t], wd_[d0 + dd], s);
    (isC ? cqp : qqp)[((size_t)blockIdx.y * NB + b) * L + i0 + t] = s;
  }
  if (!isC && blockIdx.y == 0 && t < 64) {
    const int j = i0 + t;
    mskE[(size_t)b * NLQ + j] = Qmask[b * NLQ + j] ? (short)0xFFFF : (short)0;
  }
  if (isC) {  // MT-A fragment-major store (Cafr)
    const int dt_loc = t & 1, ic_loc = (t >> 1) & 1, lane = t >> 2;
    const int dd = dt_loc * 16 + (lane & 15);
    const int ibase = ic_loc * 32 + ((lane >> 4) & 3) * 8;
    bf16x8 pk;
#pragma unroll
    for (int k = 0; k < 8; ++k) pk[k] = f2bf(T[dd][ibase + k]);
    const size_t dtile = (size_t)((d0 >> 4) + dt_loc);
    const size_t ichunk = (size_t)((i0 >> 5) + ic_loc);
    *(bf16x8*)(Cafr + (((size_t)b * 8 + dtile) * (size_t)(NLC >> 5) + ichunk) * 512 +
               (size_t)lane * 8) = pk;
  }
  // fragment-major transposed store (Cfr / Qfr, w4mlu folded on Q)
  const int i = t >> 2, seg = t & 3;
  bf16x8 pack;
#pragma unroll
  for (int k = 0; k < 8; ++k) {
    int d = seg * 8 + k;
    float x = T[d][i];
    if (!isC) x *= w4mlu[d0 + d];
    pack[k] = f2bf(x);
  }
  {
    const size_t tile = (size_t)((i0 + i) >> 4);
    const int lane = seg * 16 + ((i0 + i) & 15);
    *(bf16x8*)((isC ? Cfr : Qfr) + ((size_t)b * (L >> 4) + tile) * 2048 +
               (size_t)(d0 >> 5) * 512 + (size_t)lane * 8) = pack;
  }
}

// ---------------- k_MT: MT GEMM + E materialization, 16 waves --------------
// 1D grid 256 blocks (8 XCD x 32), 1024 thr. Double-buffered PTs ->
// one barrier per i0-iter; A-frags + next-Cf loads issued pre-barrier.
__global__ __launch_bounds__(1024) void k_MT(const short* __restrict__ Cfr,
                                             const short* __restrict__ Qfr,
                                             const short* __restrict__ Cafr,
                                             const int* __restrict__ Cmask,
                                             const float* __restrict__ cqp,
                                             const float* __restrict__ qqp,
                                             const float* __restrict__ bias,
                                             short* __restrict__ MTbf,
                                             short* __restrict__ E) {
  __shared__ short PTs[2][32 * 136];   // double-buffered P2^T bf16
  __shared__ float cspart[16][32];
  __shared__ float bc[32];
  __shared__ float mtred[8][2][64][4]; // wh=1 partial accMT (16KB)
  const int flat = blockIdx.x;                 // 256 = 8*32 exactly
  const int swz = (flat & 7) * 32 + (flat >> 3);
  const int b = swz >> 3, qt = (swz & 7) * 32;
  const int tid = threadIdx.x;
  const int w = tid >> 6, l = tid & 63, lm = l & 15, lk = l >> 4;
  const int qsub = w & 1, ioct = w >> 1;
  const int wd = w & 7, wh = w >> 3;
  const float bv = bias[0];

  bf16x8 aq[4];
  {
    const short* Qf = Qfr + ((size_t)b * 16 + (qt >> 4) + qsub) * 2048 + (size_t)l * 8;
#pragma unroll
    for (int kk = 0; kk < 4; ++kk) aq[kk] = *(const bf16x8*)(Qf + kk * 512);
  }
  float qqv[4];
#pragma unroll
  for (int r = 0; r < 4; ++r) {
    const size_t j = (size_t)b * NLQ + qt + qsub * 16 + lk * 4 + r;
    qqv[r] = qqp[j] + qqp[(size_t)NB * NLQ + j] + qqp[2 * (size_t)NB * NLQ + j] +
             qqp[3 * (size_t)NB * NLQ + j] + bv;
  }

  const int elane = (qsub * 2 + (lk >> 1)) * 16 + lm;
  short* Eb = E + (size_t)b * 128 * 4096 + (size_t)(qt >> 5) * 512 +
              (size_t)elane * 8 + (lk & 1) * 4;

  // preload first Cf tile
  bf16x8 cf[4];
  {
    const short* Cf0 = Cfr + ((size_t)b * 128 + ioct) * 2048 + (size_t)l * 8;
#pragma unroll
    for (int kk = 0; kk < 4; ++kk) cf[kk] = *(const bf16x8*)(Cf0 + kk * 512);
  }

  float csacc[4] = {0.f, 0.f, 0.f, 0.f};
  f32x4 accMT[2] = {{0.f, 0.f, 0.f, 0.f}, {0.f, 0.f, 0.f, 0.f}};
  for (int i0 = 0, it = 0; i0 < NLC; i0 += 128, ++it) {
    const int p = it & 1;
    short* PT = PTs[p];
    {
      const int iCol = i0 + ioct * 16 + lm;
      f32x4 c = {0.f, 0.f, 0.f, 0.f};
#pragma unroll
      for (int kk = 0; kk < 4; ++kk) c = MFMA16(aq[kk], cf[kk], c);
      const size_t ci = (size_t)b * NLC + iCol;
      const float cqb = cqp[ci] + cqp[(size_t)NB * NLC + ci] +
                        cqp[2 * (size_t)NB * NLC + ci] + cqp[3 * (size_t)NB * NLC + ci];
      const int cm = Cmask[b * NLC + iCol];
      short ev[4];
#pragma unroll
      for (int r = 0; r < 4; ++r) {
        float s = c[r] + cqb + qqv[r];
        float pu = __expf(s - ESHIFT);       // unmasked -> E
        float pm = cm ? pu : 0.f;            // Cmask-masked -> PTs/colsum
        csacc[r] += pm;
        PT[(qsub * 16 + lk * 4 + r) * 136 + ioct * 16 + lm] = f2bf(pm);
        ev[r] = f2bf(pu);
      }
      *(short4*)(Eb + (size_t)((i0 >> 4) + ioct) * 4096) = *(short4*)ev;
    }
    // MT-A frags for THIS iter (independent of PTs) - issue pre-barrier
    bf16x8 a4[2];
    {
      const short* Arow = Cafr + (((size_t)b * 8 + wd) * 64 + (i0 >> 5)) * 512 +
                          (size_t)(wh * 2) * 512 + (size_t)l * 8;
      a4[0] = *(const bf16x8*)Arow;
      a4[1] = *(const bf16x8*)(Arow + 512);
    }
    // next iter's Cf - issue pre-barrier
    if (i0 + 128 < NLC) {
      const short* Cfn = Cfr + ((size_t)b * 128 + (i0 >> 4) + 8 + ioct) * 2048 + (size_t)l * 8;
#pragma unroll
      for (int kk = 0; kk < 4; ++kk) cf[kk] = *(const bf16x8*)(Cfn + kk * 512);
    }
    __syncthreads();
    // MT GEMM: ks split by wh
#pragma unroll
    for (int ks2 = 0; ks2 < 2; ++ks2) {
      const int ks = wh * 2 + ks2;
#pragma unroll
      for (int qs = 0; qs < 2; ++qs) {
        bf16x8 bb = *(const bf16x8*)&PT[(qs * 16 + lm) * 136 + ks * 32 + lk * 8];
        accMT[qs] = MFMA16(a4[ks2], bb, accMT[qs]);
      }
    }
  }
  __syncthreads();
  // stash wh=1 partial accMT
  if (wh == 1) {
#pragma unroll
    for (int qs = 0; qs < 2; ++qs)
#pragma unroll
      for (int r = 0; r < 4; ++r) mtred[wd][qs][l][r] = accMT[qs][r];
  }
  // colsum reduce (all 16 waves)
#pragma unroll
  for (int off = 1; off < 16; off <<= 1)
#pragma unroll
    for (int r = 0; r < 4; ++r) csacc[r] += __shfl_xor(csacc[r], off, 64);
  if (lm == 0) {
#pragma unroll
    for (int r = 0; r < 4; ++r) cspart[w][qsub * 16 + lk * 4 + r] = csacc[r];
  }
  __syncthreads();
  if (tid < 32) {
    const int base = (tid >> 4) & 1;
    float s = 0.f;
#pragma unroll
    for (int k2 = 0; k2 < 8; ++k2) s += cspart[k2 * 2 + base][tid];
    bc[tid] = 1.0f / s;
  }
  __syncthreads();
  if (wh == 0) {
#pragma unroll
    for (int qs = 0; qs < 2; ++qs) {
#pragma unroll
      for (int r = 0; r < 4; ++r) accMT[qs][r] += mtred[wd][qs][l][r];
      const float inv = bc[qs * 16 + lm];
#pragma unroll
      for (int r = 0; r < 4; ++r)
        MTbf[((size_t)b * ND + wd * 16 + lk * 4 + r) * NLQ + qt + qs * 16 + lm] =
            f2bf(accMT[qs][r] * inv);
    }
  }
}

// ---------------- k_PAB: A/Bt GEMMs from E, LDS B-staging ------------------
// R20: 512 blocks (8 XCD x 64, bijective) x 512 thr (8 waves, 128 i-rows).
// Panels staged once per 128 rows (was 64): half the L2 panel traffic, LDS
// writes, and barriers per unit output. Inner loop identical to R19.
__global__ __launch_bounds__(512) void k_PAB(const short* __restrict__ Cafr,
                                             const short* __restrict__ E,
                                             const short* __restrict__ mskE,
                                             const short* __restrict__ Qbf,
                                             const short* __restrict__ MTbf,
                                             float* __restrict__ out) {
  __shared__ __align__(16) char Bst[32768];    // 2x16KB B-stage
  const int flat = blockIdx.x;                 // 512 = 8*64 exactly
  const int swz = (flat & 7) * 64 + (flat >> 3);
  const int b = swz >> 4, it = (swz & 15) * 128;
  const int tid = threadIdx.x;
  const int wi = tid >> 6, l = tid & 63, lm = l & 15, lk = l >> 4;

  // ---- afr from E (Qmask via AND), rowsum via shfl ----
  bf16x8 afr[8];
  {
    const short* Ef = E + ((size_t)b * 128 + (it >> 4) + wi) * 4096 + (size_t)l * 8;
    const short* mb = mskE + (size_t)b * NLQ + lk * 8;
#pragma unroll
    for (int kk = 0; kk < 8; ++kk) {
      bf16x8 a = *(const bf16x8*)(Ef + kk * 512);
      bf16x8 m = *(const bf16x8*)(mb + kk * 32);
      afr[kk] = a & m;
    }
  }
  float rsum = 0.f;
#pragma unroll
  for (int kk = 0; kk < 8; ++kk)
#pragma unroll
    for (int e = 0; e < 8; ++e) rsum += bf2f(afr[kk][e]);
  rsum += __shfl_xor(rsum, 16, 64);
  rsum += __shfl_xor(rsum, 32, 64);
  float invr[4];
#pragma unroll
  for (int r = 0; r < 4; ++r)
    invr[r] = 1.0f / __shfl(rsum, (l & 48) + lk * 4 + r, 64);

  // ---- hoisted ct loads (independent of everything below) ----
  const int iB = it + wi * 16 + lk * 4;
  const size_t cbase = ((size_t)b * 8 * 64 + (size_t)(iB >> 5)) * 512 +
                       (size_t)(((iB >> 3) & 3) * 16 + lm) * 8 + (size_t)(iB & 7);
  short4 cts[8];
#pragma unroll
  for (int n0 = 0; n0 < 8; ++n0)
    cts[n0] = *(const short4*)&Cafr[cbase + (size_t)n0 * 64 * 512];

  // ---- phase 2: double-buffered B-panel staging + MFMA + direct stores ----
  const short* Qp = Qbf + (size_t)b * ND * NLQ;
  const short* Mp = MTbf + (size_t)b * ND * NLQ;
  float* ob = out + (size_t)b * 4 * ND * NLC;

  // staging: 512 thr cover 16 rows x 32 cols of 16B per panel (8KB)
  const int srow = tid >> 5, scol = tid & 31;
  const int wsw = ((scol ^ (srow & 7)) << 4);
  const short* qsrc = Qp + (size_t)srow * NLQ + scol * 8;
  const short* msrc = Mp + (size_t)srow * NLQ + scol * 8;
  bf16x8 sq0, sm0;

#define LOADN(n0) { \
    const short* q_ = qsrc + (size_t)(n0) * 16 * NLQ; \
    const short* m_ = msrc + (size_t)(n0) * 16 * NLQ; \
    sq0 = *(const bf16x8*)q_; \
    sm0 = *(const bf16x8*)m_; }
#define WRITEN(buf) { \
    char* base_ = Bst + (buf) * 16384 + srow * 512; \
    *(bf16x8*)(base_ + wsw) = sq0; \
    *(bf16x8*)(base_ + 8192 + wsw) = sm0; }

  LOADN(0); WRITEN(0);
  __syncthreads();
#pragma unroll
  for (int n0 = 0; n0 < 8; ++n0) {
    if (n0 < 7) LOADN(n0 + 1);                 // issue next-tile loads early
    const int d = n0 * 16 + lm;
    const char* bq = Bst + (n0 & 1) * 16384 + lm * 512;
    f32x4 cA = {0.f, 0.f, 0.f, 0.f};
    f32x4 cB = {0.f, 0.f, 0.f, 0.f};
#pragma unroll
    for (int kk = 0; kk < 8; ++kk) {
      const int so = (((kk * 4 + lk) ^ (lm & 7)) << 4);
      cA = MFMA16(afr[kk], *(const bf16x8*)(bq + so), cA);
      cB = MFMA16(afr[kk], *(const bf16x8*)(bq + 8192 + so), cB);
    }
    if (n0 < 7) {
      WRITEN((n0 + 1) & 1);                    // write-late into other buffer
      __syncthreads();
    }
    float4 ct;
    ct.x = bf2f(cts[n0].x); ct.y = bf2f(cts[n0].y);
    ct.z = bf2f(cts[n0].z); ct.w = bf2f(cts[n0].w);
    float4 av, ca, cb;
    av.x = cA[0] * invr[0]; av.y = cA[1] * invr[1];
    av.z = cA[2] * invr[2]; av.w = cA[3] * invr[3];
    ca.x = ct.x * av.x; ca.y = ct.y * av.y; ca.z = ct.z * av.z; ca.w = ct.w * av.w;
    cb.x = ct.x * cB[0] * invr[0]; cb.y = ct.y * cB[1] * invr[1];
    cb.z = ct.z * cB[2] * invr[2]; cb.w = ct.w * cB[3] * invr[3];
    float* o0 = ob + (size_t)d * NLC + iB;
    *(float4*)(o0 + (size_t)128 * NLC) = av;
    *(float4*)(o0 + (size_t)256 * NLC) = ca;
    *(float4*)(o0 + (size_t)384 * NLC) = cb;
  }
#undef LOADN
#undef WRITEN
}

// ---------------------------------------------------------------------------
extern "C" void kernel_launch(void* const* d_in, const int* in_sizes, int n_in,
                              void* d_out, int out_size, void* d_ws, size_t ws_size,
                              hipStream_t stream) {
  const float* C = (const float*)d_in[0];
  const float* Q = (const float*)d_in[1];
  const int* Cmask = (const int*)d_in[2];
  const int* Qmask = (const int*)d_in[3];
  const float* w4C = (const float*)d_in[4];
  const float* w4Q = (const float*)d_in[5];
  const float* w4mlu = (const float*)d_in[6];
  const float* bias = (const float*)d_in[7];
  float* out = (float*)d_out;

  short* Cfr = (short*)d_ws;                           // [b][128 tiles][4][64][8]
  short* Cafr = Cfr + (size_t)NB * NLC * ND;           // [b][8 dt][64 ic][64][8]
  short* Qfr = Cafr + (size_t)NB * NLC * ND;           // [b][16 tiles][4][64][8] (w4mlu folded)
  short* Qbf = Qfr + (size_t)NB * NLQ * ND;            // [b][D][Lq]
  short* MTbf = Qbf + (size_t)NB * NLQ * ND;           // [b][D][Lq]
  short* E = MTbf + (size_t)NB * ND * NLQ;             // [b][128 it][8 kk][64][8]
  short* mskE = E + (size_t)NB * NLC * NLQ;            // [b][256]
  float* cqp = (float*)(mskE + (size_t)NB * NLQ);      // [4][b][Lc] partials
  float* qqp = cqp + 4 * (size_t)NB * NLC;             // [4][b][Lq] partials
  size_t need = (size_t)(qqp + 4 * NB * NLQ - (float*)d_ws) * sizeof(float);
  if (ws_size < need) return;  // fail loudly rather than corrupt

  k_tr<<<dim3(36, 4, NB), 256, 0, stream>>>(C, Q, w4C, w4Q, w4mlu, Cfr, Cafr, Qfr, Qbf,
                                            cqp, qqp, Qmask, mskE, out);
  k_MT<<<256, 1024, 0, stream>>>(Cfr, Qfr, Cafr, Cmask, cqp, qqp, bias, MTbf, E);
  k_PAB<<<512, 512, 0, stream>>>(Cafr, E, mskE, Qbf, MTbf, out);
}